// Round 1
// baseline (24636.798 us; speedup 1.0000x reference)
//
#include <hip/hip_runtime.h>
#include <math.h>

#define NVAR  20000
#define NVAL  160000
#define NCST  20000
#define NEDGE 160000
#define HD    128

static __device__ __forceinline__ float sigmoidf_(float x) {
    return 1.0f / (1.0f + expf(-x));
}

// ---------------------------------------------------------------------------
// elementwise / small kernels
// ---------------------------------------------------------------------------

__global__ __launch_bounds__(256) void k_init_h(float* __restrict__ h,
                                                const float* __restrict__ hinit) {
    size_t i = (size_t)blockIdx.x * 256 + threadIdx.x;   // grid covers NVAL*HD exactly
    h[i] = hinit[i & (HD - 1)];
}

__global__ __launch_bounds__(256) void k_agg(const float* __restrict__ y,
                                             float* __restrict__ agg) {
    size_t i = (size_t)blockIdx.x * 256 + threadIdx.x;   // over NVAR*HD exactly
    int var = (int)(i >> 7);
    int c   = (int)(i & (HD - 1));
    const float* base = y + ((size_t)var * 8) * HD + c;
    float s = 0.f;
#pragma unroll
    for (int d = 0; d < 8; ++d) s += base[(size_t)d * HD];
    agg[i] = s * 0.125f;
}

__global__ __launch_bounds__(256) void k_sample(const float* __restrict__ logits,
                                                const float* __restrict__ g,
                                                float* __restrict__ assign,
                                                float* __restrict__ lp_accum) {
    int v = blockIdx.x * 256 + threadIdx.x;
    float lp = 0.f;
    if (v < NVAR) {
        float lg[8];
        int choice = 0;
        float bestv = -1e30f;
#pragma unroll
        for (int d = 0; d < 8; ++d) {
            lg[d] = logits ? logits[v * 8 + d] : 0.f;
            float t = lg[d] + g[v * 8 + d];
            if (t > bestv) { bestv = t; choice = d; }   // strict > keeps first max (jnp.argmax)
        }
        float m = lg[0];
#pragma unroll
        for (int d = 1; d < 8; ++d) m = fmaxf(m, lg[d]);
        float se = 0.f;
#pragma unroll
        for (int d = 0; d < 8; ++d) se += expf(lg[d] - m);
        lp = lg[choice] - m - logf(se);
#pragma unroll
        for (int d = 0; d < 8; ++d) assign[v * 8 + d] = (d == choice) ? 1.f : 0.f;
    }
    __shared__ float sred[256];
    sred[threadIdx.x] = lp;
    __syncthreads();
    for (int o = 128; o > 0; o >>= 1) {
        if (threadIdx.x < o) sred[threadIdx.x] += sred[threadIdx.x + o];
        __syncthreads();
    }
    if (threadIdx.x == 0) atomicAdd(lp_accum, sred[0]);
}

__global__ __launch_bounds__(256) void k_unsat(const float* __restrict__ assign,
                                               const int* __restrict__ val_idx,
                                               int* __restrict__ sat_accum) {
    int c = blockIdx.x * 256 + threadIdx.x;
    int sat = 0;
    if (c < NCST) {
#pragma unroll
        for (int j = 0; j < 8; ++j)
            if (assign[val_idx[c * 8 + j]] > 0.5f) sat = 1;
    }
    __shared__ int sred[256];
    sred[threadIdx.x] = sat;
    __syncthreads();
    for (int o = 128; o > 0; o >>= 1) {
        if (threadIdx.x < o) sred[threadIdx.x] += sred[threadIdx.x + o];
        __syncthreads();
    }
    if (threadIdx.x == 0) atomicAdd(sat_accum, sred[0]);
}

__global__ void k_finalize(const float* __restrict__ lp, const int* __restrict__ sat,
                           float* __restrict__ best, float* __restrict__ out,
                           int s, int S, int mode) {
    float nu = (float)NCST - (float)(*sat);
    if (mode == 0) {
        *best = nu;                      // best0 = num_unsat(assign0)
    } else {
        out[s] = *lp;
        out[S + s] = nu;
        float b = *best;
        if (nu < b) b = nu;
        *best = b;
        if (s == S - 1) out[2 * S] = b;
    }
}

__global__ void k_report(float* out, float v) {
    for (int i = 0; i < 9; ++i) out[i] = v;
}

// ---------------------------------------------------------------------------
// generic f32 GEMM tile kernel: 64 rows x 128 cols per block, K in {128,256}
// A-row sources: direct / gather(idx) / idx = row>>3.  Optional 129th "assign
// bit" rank-1 term (W1 row 128).  Epilogues: store / group-8 row-sum (r_cst) /
// atomic scatter-add by idx (y_val) / policy dot with Wp2 -> logits.
// ---------------------------------------------------------------------------

static constexpr int AM_NONE = 0, AM_DIRECT = 1, AM_GATHER = 2, AM_DIV8 = 3;
static constexpr int EPI_STORE = 0, EPI_RCST = 1, EPI_SCATTER = 2, EPI_POLICY = 3;

template <int A0M, int A1M, bool BIT, bool RELU, int EPI>
__global__ __launch_bounds__(256)
void gemm_k(const float* __restrict__ A0, const float* __restrict__ A1,
            const int* __restrict__ aidx, const float* __restrict__ abit,
            const float* __restrict__ B0, int ldb, int bcol0,
            const float* __restrict__ bias0,
            float* __restrict__ Cout, int ldc,
            float* __restrict__ out2, const float* __restrict__ wp2) {
    constexpr int K = (A1M == AM_NONE) ? 128 : 256;
    __shared__ float a_lds[64][36];
    __shared__ float b_lds[32][132];
    __shared__ int   idx_lds[64];
    __shared__ float bit_lds[64];

    const int tid   = threadIdx.x;
    const int row0  = blockIdx.x * 64;
    const int scol0 = blockIdx.y * 128;

    if constexpr (A0M == AM_GATHER || A1M == AM_GATHER || EPI == EPI_SCATTER) {
        if (tid < 64) {
            int ix = aidx[row0 + tid];
            idx_lds[tid] = ix;
            if constexpr (BIT) bit_lds[tid] = abit[ix];
        }
    }

    const int rg = tid >> 4;   // 16 groups x 4 rows
    const int cg = tid & 15;   // 16 groups x 8 cols
    float acc[4][8] = {};

    for (int kc = 0; kc < K; kc += 32) {
        __syncthreads();
        // stage A tile (64 rows x 32 k)
        for (int i = tid; i < 64 * 32; i += 256) {
            int r = i >> 5, kk = i & 31;
            int gk = kc + kk;
            float v = 0.f;
            if (gk < 128) {
                if constexpr (A0M == AM_DIRECT)      v = A0[(size_t)(row0 + r) * HD + gk];
                else if constexpr (A0M == AM_GATHER) v = A0[(size_t)idx_lds[r] * HD + gk];
                else if constexpr (A0M == AM_DIV8)   v = A0[(size_t)((row0 + r) >> 3) * HD + gk];
            } else {
                int k1 = gk - 128;
                if constexpr (A1M == AM_DIRECT)      v = A1[(size_t)(row0 + r) * HD + k1];
                else if constexpr (A1M == AM_GATHER) v = A1[(size_t)idx_lds[r] * HD + k1];
                else if constexpr (A1M == AM_DIV8)   v = A1[(size_t)((row0 + r) >> 3) * HD + k1];
            }
            a_lds[r][kk] = v;
        }
        // stage B tile (32 k x 128 cols)
        for (int i = tid; i < 32 * 128; i += 256) {
            int kk = i >> 7, c = i & 127;
            int gk = kc + kk;
            b_lds[kk][c] = B0[(size_t)gk * ldb + bcol0 + scol0 + c];
        }
        __syncthreads();
#pragma unroll
        for (int kk = 0; kk < 32; ++kk) {
            float bv[8];
#pragma unroll
            for (int j = 0; j < 8; ++j) bv[j] = b_lds[kk][cg * 8 + j];
#pragma unroll
            for (int i = 0; i < 4; ++i) {
                float av = a_lds[rg * 4 + i][kk];
#pragma unroll
                for (int j = 0; j < 8; ++j) acc[i][j] = fmaf(av, bv[j], acc[i][j]);
            }
        }
    }

    if constexpr (BIT) {   // 129th input: assign bit * W1 row 128
        float wb[8];
#pragma unroll
        for (int j = 0; j < 8; ++j) wb[j] = B0[(size_t)HD * ldb + bcol0 + scol0 + cg * 8 + j];
#pragma unroll
        for (int i = 0; i < 4; ++i) {
            float ab = bit_lds[rg * 4 + i];
#pragma unroll
            for (int j = 0; j < 8; ++j) acc[i][j] = fmaf(ab, wb[j], acc[i][j]);
        }
    }

    if (bias0 != nullptr) {
#pragma unroll
        for (int j = 0; j < 8; ++j) {
            float bv = bias0[bcol0 + scol0 + cg * 8 + j];
#pragma unroll
            for (int i = 0; i < 4; ++i) acc[i][j] += bv;
        }
    }
    if constexpr (RELU) {
#pragma unroll
        for (int i = 0; i < 4; ++i)
#pragma unroll
            for (int j = 0; j < 8; ++j) acc[i][j] = fmaxf(acc[i][j], 0.f);
    }

    if constexpr (EPI == EPI_STORE) {
#pragma unroll
        for (int i = 0; i < 4; ++i) {
            size_t rbase = (size_t)(row0 + rg * 4 + i) * ldc + scol0 + cg * 8;
#pragma unroll
            for (int j = 0; j < 8; ++j) Cout[rbase + j] = acc[i][j];
        }
    } else if constexpr (EPI == EPI_RCST) {
        // sum groups of 8 consecutive rows (one constraint each) -> out2
        __shared__ float red[16][129];
#pragma unroll
        for (int j = 0; j < 8; ++j)
            red[rg][cg * 8 + j] = acc[0][j] + acc[1][j] + acc[2][j] + acc[3][j];
        __syncthreads();
        for (int i = tid; i < 8 * 128; i += 256) {
            int q = i >> 7, c = i & 127;
            out2[(size_t)((row0 >> 3) + q) * HD + c] = red[2 * q][c] + red[2 * q + 1][c];
        }
    } else if constexpr (EPI == EPI_SCATTER) {
#pragma unroll
        for (int i = 0; i < 4; ++i) {
            int tgt = idx_lds[rg * 4 + i];
            float* dst = Cout + (size_t)tgt * HD + cg * 8;
#pragma unroll
            for (int j = 0; j < 8; ++j) atomicAdd(&dst[j], acc[i][j]);
        }
    } else {  // EPI_POLICY: logits[row] = sum_c acc[row][c] * wp2[c]
        __shared__ float red[64][17];
        float w[8];
#pragma unroll
        for (int j = 0; j < 8; ++j) w[j] = wp2[cg * 8 + j];
#pragma unroll
        for (int i = 0; i < 4; ++i) {
            float s = 0.f;
#pragma unroll
            for (int j = 0; j < 8; ++j) s = fmaf(acc[i][j], w[j], s);
            red[rg * 4 + i][cg] = s;
        }
        __syncthreads();
        if (tid < 64) {
            float s = 0.f;
#pragma unroll
            for (int t2 = 0; t2 < 16; ++t2) s += red[tid][t2];
            out2[row0 + tid] = s;
        }
    }
}

// ---------------------------------------------------------------------------
// fused GRU: h = GRU(z, h) in place.  32 rows/block; accumulates the r-gate,
// z-gate, input-n (z@Wi_n, K-half 0) and hidden-n (h@Wh_n, K-half 1) blocks
// separately, then applies gates.  A = [z ; h] over K=256; B per K-half is
// the full 384-col row slab of Wi or Wh.
// ---------------------------------------------------------------------------
__global__ __launch_bounds__(256)
void k_gru(const float* __restrict__ Z, float* __restrict__ Hb,
           const float* __restrict__ Wi, const float* __restrict__ Wh,
           const float* __restrict__ bi, const float* __restrict__ bh) {
    __shared__ float a_lds[32][36];
    __shared__ float b_lds[32][388];

    const int tid  = threadIdx.x;
    const int row0 = blockIdx.x * 32;
    const int rg = tid >> 4;   // 16 groups x 2 rows
    const int cg = tid & 15;   // 16 groups x 8 cols

    float accR[2][8] = {}, accZ[2][8] = {}, accN[2][8] = {}, accH[2][8] = {};

    for (int kc = 0; kc < 256; kc += 32) {
        __syncthreads();
        for (int i = tid; i < 32 * 32; i += 256) {
            int r = i >> 5, kk = i & 31;
            int gk = kc + kk;
            a_lds[r][kk] = (gk < 128) ? Z[(size_t)(row0 + r) * HD + gk]
                                      : Hb[(size_t)(row0 + r) * HD + (gk - 128)];
        }
        const float* Wsrc = (kc < 128) ? Wi : Wh;
        const int krow0   = (kc < 128) ? kc : (kc - 128);
        for (int i = tid; i < 32 * 384; i += 256) {
            int kk = i / 384;
            int c  = i - kk * 384;
            b_lds[kk][c] = Wsrc[(size_t)(krow0 + kk) * 384 + c];
        }
        __syncthreads();
        const bool lowK = (kc < 128);
#pragma unroll
        for (int kk = 0; kk < 32; ++kk) {
            float a0 = a_lds[rg * 2 + 0][kk];
            float a1 = a_lds[rg * 2 + 1][kk];
            float bv[8];
#pragma unroll
            for (int j = 0; j < 8; ++j) bv[j] = b_lds[kk][cg * 8 + j];
#pragma unroll
            for (int j = 0; j < 8; ++j) {
                accR[0][j] = fmaf(a0, bv[j], accR[0][j]);
                accR[1][j] = fmaf(a1, bv[j], accR[1][j]);
            }
#pragma unroll
            for (int j = 0; j < 8; ++j) bv[j] = b_lds[kk][128 + cg * 8 + j];
#pragma unroll
            for (int j = 0; j < 8; ++j) {
                accZ[0][j] = fmaf(a0, bv[j], accZ[0][j]);
                accZ[1][j] = fmaf(a1, bv[j], accZ[1][j]);
            }
#pragma unroll
            for (int j = 0; j < 8; ++j) bv[j] = b_lds[kk][256 + cg * 8 + j];
            if (lowK) {
#pragma unroll
                for (int j = 0; j < 8; ++j) {
                    accN[0][j] = fmaf(a0, bv[j], accN[0][j]);
                    accN[1][j] = fmaf(a1, bv[j], accN[1][j]);
                }
            } else {
#pragma unroll
                for (int j = 0; j < 8; ++j) {
                    accH[0][j] = fmaf(a0, bv[j], accH[0][j]);
                    accH[1][j] = fmaf(a1, bv[j], accH[1][j]);
                }
            }
        }
    }

#pragma unroll
    for (int i = 0; i < 2; ++i) {
        int r = row0 + rg * 2 + i;
#pragma unroll
        for (int j = 0; j < 8; ++j) {
            int c = cg * 8 + j;
            float rr = sigmoidf_(accR[i][j] + bi[c] + bh[c]);
            float zz = sigmoidf_(accZ[i][j] + bi[128 + c] + bh[128 + c]);
            float nn = tanhf(accN[i][j] + bi[256 + c] + rr * (accH[i][j] + bh[256 + c]));
            size_t off = (size_t)r * HD + c;
            float hv = Hb[off];
            Hb[off] = (1.f - zz) * nn + zz * hv;
        }
    }
}

// ---------------------------------------------------------------------------
extern "C" void kernel_launch(void* const* d_in, const int* in_sizes, int n_in,
                              void* d_out, int out_size, void* d_ws, size_t ws_size,
                              hipStream_t stream) {
    const float* h_init = (const float*)d_in[0];
    const float* W1  = (const float*)d_in[1];
    const float* b1  = (const float*)d_in[2];
    const float* W2  = (const float*)d_in[3];
    const float* Wx  = (const float*)d_in[4];
    const float* bx  = (const float*)d_in[5];
    const float* Wc  = (const float*)d_in[6];
    const float* bc  = (const float*)d_in[7];
    const float* Wv  = (const float*)d_in[8];
    const float* bv  = (const float*)d_in[9];
    const float* Wi  = (const float*)d_in[10];
    const float* Wh  = (const float*)d_in[11];
    const float* bi  = (const float*)d_in[12];
    const float* bh  = (const float*)d_in[13];
    const float* Wp1 = (const float*)d_in[14];
    const float* bp1 = (const float*)d_in[15];
    const float* Wp2 = (const float*)d_in[16];
    const float* gum = (const float*)d_in[17];
    const int* val_idx = (const int*)d_in[18];
    // d_in[19] = cst_idx (known structure: e/8), d_in[20] = steps (device scalar)
    float* out = (float*)d_out;

    const int S = (out_size - 1) / 2;    // log_probs[S], unsat[S], best

    const size_t VH = (size_t)NVAL * HD;
    float* ws     = (float*)d_ws;
    float* h      = ws;
    float* tA     = ws + VH;
    float* tB     = ws + 2 * VH;
    float* rcst   = ws + 3 * VH;
    float* agg    = rcst + (size_t)NCST * HD;
    float* assign = agg + (size_t)NVAR * HD;
    float* logits = assign + NVAL;
    float* lp_acc = logits + NVAL;            // 8 floats
    int*   sat    = (int*)(lp_acc + 8);       // 8 ints
    float* best   = (float*)(sat + 8);        // 1 float

    const size_t needed = ((3 * VH) + (size_t)NCST * HD + (size_t)NVAR * HD +
                           2 * (size_t)NVAL + 32) * sizeof(float);
    if (ws_size < needed) {  // diagnostic: expose ws_size through d_out
        k_report<<<1, 1, 0, stream>>>(out, (float)ws_size);
        return;
    }

    (void)hipMemsetAsync(lp_acc, 0, 17 * sizeof(float), stream);

    const dim3 B256(256);
    const dim3 gV(NVAL / 64);        // 2500
    const dim3 gE(NEDGE / 64);       // 2500
    const dim3 gVar((NVAR + 255) / 256);

    k_init_h<<<dim3(NVAL * HD / 256), B256, 0, stream>>>(h, h_init);
    k_sample<<<gVar, B256, 0, stream>>>(nullptr, gum, assign, lp_acc);
    k_unsat<<<gVar, B256, 0, stream>>>(assign, val_idx, sat);
    k_finalize<<<1, 1, 0, stream>>>(lp_acc, sat, best, out, 0, S, 0);

    for (int s = 0; s < S; ++s) {
        const int t = s + 1;
        // 1. H1 = relu([h[val_idx] | assign_bit] @ W1 + b1) -> tA
        gemm_k<AM_GATHER, AM_NONE, true, true, EPI_STORE><<<gE, B256, 0, stream>>>(
            h, nullptr, val_idx, assign, W1, HD, 0, b1, tA, HD, nullptr, nullptr);
        // 2. r_cst = groupsum8(H1 @ W2)
        gemm_k<AM_DIRECT, AM_NONE, false, false, EPI_RCST><<<gE, B256, 0, stream>>>(
            tA, nullptr, nullptr, nullptr, W2, HD, 0, nullptr, nullptr, HD, rcst, nullptr);
        // 3. x_val = relu(h @ Wx + bx) -> tA
        gemm_k<AM_DIRECT, AM_NONE, false, true, EPI_STORE><<<gV, B256, 0, stream>>>(
            h, nullptr, nullptr, nullptr, Wx, HD, 0, bx, tA, HD, nullptr, nullptr);
        // 4. y_val = scatter_add(relu([r_cst[e/8] | x_val[val_idx]] @ Wc + bc))
        (void)hipMemsetAsync(tB, 0, VH * sizeof(float), stream);
        gemm_k<AM_DIV8, AM_GATHER, false, true, EPI_SCATTER><<<gE, B256, 0, stream>>>(
            rcst, tA, val_idx, nullptr, Wc, HD, 0, bc, tB, HD, nullptr, nullptr);
        // 5. agg = mean over domain
        k_agg<<<dim3(NVAR * HD / 256), B256, 0, stream>>>(tB, agg);
        // 6. z = relu([y_val | agg[v/8]] @ Wv + bv) -> tA
        gemm_k<AM_DIRECT, AM_DIV8, false, true, EPI_STORE><<<gV, B256, 0, stream>>>(
            tB, agg, nullptr, nullptr, Wv, HD, 0, bv, tA, HD, nullptr, nullptr);
        // 7. h = GRU(z, h) (fused, in place)
        k_gru<<<dim3(NVAL / 32), B256, 0, stream>>>(tA, h, Wi, Wh, bi, bh);
        // 8. logits = relu(h @ Wp1 + bp1) @ Wp2
        gemm_k<AM_DIRECT, AM_NONE, false, true, EPI_POLICY><<<gV, B256, 0, stream>>>(
            h, nullptr, nullptr, nullptr, Wp1, HD, 0, bp1, nullptr, HD, logits, Wp2);
        // 9. sample / unsat / outputs
        k_sample<<<gVar, B256, 0, stream>>>(logits, gum + (size_t)t * NVAL, assign, lp_acc + t);
        k_unsat<<<gVar, B256, 0, stream>>>(assign, val_idx, sat + t);
        k_finalize<<<1, 1, 0, stream>>>(lp_acc + t, sat + t, best, out, s, S, 1);
    }
}

// Round 2
// 10027.622 us; speedup vs baseline: 2.4569x; 2.4569x over previous
//
#include <hip/hip_runtime.h>
#include <math.h>

#define NVAR  20000
#define NVAL  160000
#define NCST  20000
#define NEDGE 160000
#define HD    128

static __device__ __forceinline__ float sigmoidf_(float x) {
    return 1.0f / (1.0f + expf(-x));
}

// ---------------------------------------------------------------------------
// elementwise / small kernels
// ---------------------------------------------------------------------------

__global__ __launch_bounds__(256) void k_init_h(float* __restrict__ h,
                                                const float* __restrict__ hinit) {
    size_t i = (size_t)blockIdx.x * 256 + threadIdx.x;   // grid covers NVAL*HD exactly
    h[i] = hinit[i & (HD - 1)];
}

__global__ __launch_bounds__(256) void k_agg(const float* __restrict__ y,
                                             float* __restrict__ agg) {
    size_t i = (size_t)blockIdx.x * 256 + threadIdx.x;   // over NVAR*HD exactly
    int var = (int)(i >> 7);
    int c   = (int)(i & (HD - 1));
    const float* base = y + ((size_t)var * 8) * HD + c;
    float s = 0.f;
#pragma unroll
    for (int d = 0; d < 8; ++d) s += base[(size_t)d * HD];
    agg[i] = s * 0.125f;
}

__global__ __launch_bounds__(256) void k_sample(const float* __restrict__ logits,
                                                const float* __restrict__ g,
                                                float* __restrict__ assign,
                                                float* __restrict__ lp_accum) {
    int v = blockIdx.x * 256 + threadIdx.x;
    float lp = 0.f;
    if (v < NVAR) {
        float lg[8];
        int choice = 0;
        float bestv = -1e30f;
#pragma unroll
        for (int d = 0; d < 8; ++d) {
            lg[d] = logits ? logits[v * 8 + d] : 0.f;
            float t = lg[d] + g[v * 8 + d];
            if (t > bestv) { bestv = t; choice = d; }   // strict > keeps first max (jnp.argmax)
        }
        float m = lg[0];
#pragma unroll
        for (int d = 1; d < 8; ++d) m = fmaxf(m, lg[d]);
        float se = 0.f;
#pragma unroll
        for (int d = 0; d < 8; ++d) se += expf(lg[d] - m);
        lp = lg[choice] - m - logf(se);
#pragma unroll
        for (int d = 0; d < 8; ++d) assign[v * 8 + d] = (d == choice) ? 1.f : 0.f;
    }
    __shared__ float sred[256];
    sred[threadIdx.x] = lp;
    __syncthreads();
    for (int o = 128; o > 0; o >>= 1) {
        if (threadIdx.x < o) sred[threadIdx.x] += sred[threadIdx.x + o];
        __syncthreads();
    }
    if (threadIdx.x == 0) atomicAdd(lp_accum, sred[0]);
}

__global__ __launch_bounds__(256) void k_unsat(const float* __restrict__ assign,
                                               const int* __restrict__ val_idx,
                                               int* __restrict__ sat_accum) {
    int c = blockIdx.x * 256 + threadIdx.x;
    int sat = 0;
    if (c < NCST) {
#pragma unroll
        for (int j = 0; j < 8; ++j)
            if (assign[val_idx[c * 8 + j]] > 0.5f) sat = 1;
    }
    __shared__ int sred[256];
    sred[threadIdx.x] = sat;
    __syncthreads();
    for (int o = 128; o > 0; o >>= 1) {
        if (threadIdx.x < o) sred[threadIdx.x] += sred[threadIdx.x + o];
        __syncthreads();
    }
    if (threadIdx.x == 0) atomicAdd(sat_accum, sred[0]);
}

__global__ void k_finalize(const float* __restrict__ lp, const int* __restrict__ sat,
                           float* __restrict__ best, float* __restrict__ out,
                           int s, int S, int mode) {
    float nu = (float)NCST - (float)(*sat);
    if (mode == 0) {
        *best = nu;                      // best0 = num_unsat(assign0)
    } else {
        out[s] = *lp;
        out[S + s] = nu;
        float b = *best;
        if (nu < b) b = nu;
        *best = b;
        if (s == S - 1) out[2 * S] = b;
    }
}

__global__ void k_report(float* out, float v) {
    for (int i = 0; i < 9; ++i) out[i] = v;
}

// ---------------------------------------------------------------------------
// generic f32 GEMM tile kernel: 64 rows x 128 cols per block, K in {128,256}
// ---------------------------------------------------------------------------

static constexpr int AM_NONE = 0, AM_DIRECT = 1, AM_GATHER = 2, AM_DIV8 = 3;
static constexpr int EPI_STORE = 0, EPI_RCST = 1, EPI_SCATTER = 2, EPI_POLICY = 3;

template <int A0M, int A1M, bool BIT, bool RELU, int EPI>
__global__ __launch_bounds__(256)
void gemm_k(const float* __restrict__ A0, const float* __restrict__ A1,
            const int* __restrict__ aidx, const float* __restrict__ abit,
            const float* __restrict__ B0, int ldb, int bcol0,
            const float* __restrict__ bias0,
            float* __restrict__ Cout, int ldc,
            float* __restrict__ out2, const float* __restrict__ wp2) {
    constexpr int K = (A1M == AM_NONE) ? 128 : 256;
    __shared__ float a_lds[64][36];
    __shared__ float b_lds[32][132];
    __shared__ int   idx_lds[64];
    __shared__ float bit_lds[64];

    const int tid   = threadIdx.x;
    const int row0  = blockIdx.x * 64;
    const int scol0 = blockIdx.y * 128;

    if constexpr (A0M == AM_GATHER || A1M == AM_GATHER || EPI == EPI_SCATTER) {
        if (tid < 64) {
            int ix = aidx[row0 + tid];
            idx_lds[tid] = ix;
            if constexpr (BIT) bit_lds[tid] = abit[ix];
        }
    }

    const int rg = tid >> 4;   // 16 groups x 4 rows
    const int cg = tid & 15;   // 16 groups x 8 cols
    float acc[4][8] = {};

    for (int kc = 0; kc < K; kc += 32) {
        __syncthreads();
        // stage A tile (64 rows x 32 k)
        for (int i = tid; i < 64 * 32; i += 256) {
            int r = i >> 5, kk = i & 31;
            int gk = kc + kk;
            float v = 0.f;
            if (gk < 128) {
                if constexpr (A0M == AM_DIRECT)      v = A0[(size_t)(row0 + r) * HD + gk];
                else if constexpr (A0M == AM_GATHER) v = A0[(size_t)idx_lds[r] * HD + gk];
                else if constexpr (A0M == AM_DIV8)   v = A0[(size_t)((row0 + r) >> 3) * HD + gk];
            } else {
                int k1 = gk - 128;
                if constexpr (A1M == AM_DIRECT)      v = A1[(size_t)(row0 + r) * HD + k1];
                else if constexpr (A1M == AM_GATHER) v = A1[(size_t)idx_lds[r] * HD + k1];
                else if constexpr (A1M == AM_DIV8)   v = A1[(size_t)((row0 + r) >> 3) * HD + k1];
            }
            a_lds[r][kk] = v;
        }
        // stage B tile (32 k x 128 cols)
        for (int i = tid; i < 32 * 128; i += 256) {
            int kk = i >> 7, c = i & 127;
            int gk = kc + kk;
            b_lds[kk][c] = B0[(size_t)gk * ldb + bcol0 + scol0 + c];
        }
        __syncthreads();
#pragma unroll
        for (int kk = 0; kk < 32; ++kk) {
            float bv[8];
#pragma unroll
            for (int j = 0; j < 8; ++j) bv[j] = b_lds[kk][cg * 8 + j];
#pragma unroll
            for (int i = 0; i < 4; ++i) {
                float av = a_lds[rg * 4 + i][kk];
#pragma unroll
                for (int j = 0; j < 8; ++j) acc[i][j] = fmaf(av, bv[j], acc[i][j]);
            }
        }
    }

    if constexpr (BIT) {   // 129th input: assign bit * W1 row 128
        float wb[8];
#pragma unroll
        for (int j = 0; j < 8; ++j) wb[j] = B0[(size_t)HD * ldb + bcol0 + scol0 + cg * 8 + j];
#pragma unroll
        for (int i = 0; i < 4; ++i) {
            float ab = bit_lds[rg * 4 + i];
#pragma unroll
            for (int j = 0; j < 8; ++j) acc[i][j] = fmaf(ab, wb[j], acc[i][j]);
        }
    }

    if (bias0 != nullptr) {
#pragma unroll
        for (int j = 0; j < 8; ++j) {
            float bv = bias0[bcol0 + scol0 + cg * 8 + j];
#pragma unroll
            for (int i = 0; i < 4; ++i) acc[i][j] += bv;
        }
    }
    if constexpr (RELU) {
#pragma unroll
        for (int i = 0; i < 4; ++i)
#pragma unroll
            for (int j = 0; j < 8; ++j) acc[i][j] = fmaxf(acc[i][j], 0.f);
    }

    if constexpr (EPI == EPI_STORE) {
#pragma unroll
        for (int i = 0; i < 4; ++i) {
            size_t rbase = (size_t)(row0 + rg * 4 + i) * ldc + scol0 + cg * 8;
#pragma unroll
            for (int j = 0; j < 8; ++j) Cout[rbase + j] = acc[i][j];
        }
    } else if constexpr (EPI == EPI_RCST) {
        // sum groups of 8 consecutive rows (one constraint each) -> out2
        __shared__ float red[16][129];
#pragma unroll
        for (int j = 0; j < 8; ++j)
            red[rg][cg * 8 + j] = acc[0][j] + acc[1][j] + acc[2][j] + acc[3][j];
        __syncthreads();
        for (int i = tid; i < 8 * 128; i += 256) {
            int q = i >> 7, c = i & 127;
            out2[(size_t)((row0 >> 3) + q) * HD + c] = red[2 * q][c] + red[2 * q + 1][c];
        }
    } else if constexpr (EPI == EPI_SCATTER) {
#pragma unroll
        for (int i = 0; i < 4; ++i) {
            int tgt = idx_lds[rg * 4 + i];
            float* dst = Cout + (size_t)tgt * HD + cg * 8;
#pragma unroll
            for (int j = 0; j < 8; ++j) atomicAdd(&dst[j], acc[i][j]);
        }
    } else {  // EPI_POLICY: logits[row] = sum_c acc[row][c] * wp2[c]
        __shared__ float red[64][17];
        float w[8];
#pragma unroll
        for (int j = 0; j < 8; ++j) w[j] = wp2[cg * 8 + j];
#pragma unroll
        for (int i = 0; i < 4; ++i) {
            float s = 0.f;
#pragma unroll
            for (int j = 0; j < 8; ++j) s = fmaf(acc[i][j], w[j], s);
            red[rg * 4 + i][cg] = s;
        }
        __syncthreads();
        if (tid < 64) {
            float s = 0.f;
#pragma unroll
            for (int t2 = 0; t2 < 16; ++t2) s += red[tid][t2];
            out2[row0 + tid] = s;
        }
    }
}

// ---------------------------------------------------------------------------
// fused GRU v2: h = GRU(z, h) in place.
// 1024 threads/block, 64 rows x 384 cols per block.  Each thread owns ONE row
// (rw = tid>>4) and 8 cols in each of the 3 gate slabs (cg = tid&15):
// 32 accumulators total (aR, aZ, aN, aH) -> no spill (vs 64 accs/256 VGPR in v1).
// K=256 processed as two clean halves: half0 A=Z,W=Wi (accN for n-slab),
// half1 A=H,W=Wh (accH for n-slab).  In-place safe: block only reads its own
// 64 rows of H, and all H reads complete before the final in-loop barrier.
// ---------------------------------------------------------------------------
#define GRU_HALF(ASRC, WSRC, ACCN)                                              \
    for (int kc = 0; kc < 128; kc += 32) {                                      \
        __syncthreads();                                                        \
        for (int i = tid; i < 64 * 32; i += 1024) {                             \
            int r = i >> 5, kk = i & 31;                                        \
            a_lds[r][kk] = ASRC[(size_t)(row0 + r) * HD + kc + kk];             \
        }                                                                       \
        for (int i = tid; i < 32 * 384; i += 1024) {                            \
            int kk = i / 384, c = i - kk * 384;                                 \
            b_lds[kk][c] = WSRC[(size_t)(kc + kk) * 384 + c];                   \
        }                                                                       \
        __syncthreads();                                                        \
        _Pragma("unroll")                                                       \
        for (int kk = 0; kk < 32; ++kk) {                                       \
            float av = a_lds[rw][kk];                                           \
            const float* brow = &b_lds[kk][0];                                  \
            _Pragma("unroll")                                                   \
            for (int j = 0; j < 8; ++j)                                         \
                aR[j] = fmaf(av, brow[cg * 8 + j], aR[j]);                      \
            _Pragma("unroll")                                                   \
            for (int j = 0; j < 8; ++j)                                         \
                aZ[j] = fmaf(av, brow[128 + cg * 8 + j], aZ[j]);                \
            _Pragma("unroll")                                                   \
            for (int j = 0; j < 8; ++j)                                         \
                ACCN[j] = fmaf(av, brow[256 + cg * 8 + j], ACCN[j]);            \
        }                                                                       \
    }

__global__ __launch_bounds__(1024)
void k_gru2(const float* __restrict__ Z, float* __restrict__ Hb,
            const float* __restrict__ Wi, const float* __restrict__ Wh,
            const float* __restrict__ bi, const float* __restrict__ bh) {
    __shared__ float a_lds[64][33];
    __shared__ float b_lds[32][388];

    const int tid  = threadIdx.x;
    const int row0 = blockIdx.x * 64;
    const int rw = tid >> 4;   // row within tile (0..63)
    const int cg = tid & 15;   // col group (8 cols per slab)

    float aR[8] = {}, aZ[8] = {}, aN[8] = {}, aH[8] = {};

    GRU_HALF(Z,  Wi, aN)
    GRU_HALF(Hb, Wh, aH)

    const int r = row0 + rw;
#pragma unroll
    for (int j = 0; j < 8; ++j) {
        int c = cg * 8 + j;
        float rr = sigmoidf_(aR[j] + bi[c] + bh[c]);
        float zz = sigmoidf_(aZ[j] + bi[128 + c] + bh[128 + c]);
        float nn = tanhf(aN[j] + bi[256 + c] + rr * (aH[j] + bh[256 + c]));
        size_t off = (size_t)r * HD + c;
        float hv = Hb[off];
        Hb[off] = (1.f - zz) * nn + zz * hv;
    }
}

// ---------------------------------------------------------------------------
extern "C" void kernel_launch(void* const* d_in, const int* in_sizes, int n_in,
                              void* d_out, int out_size, void* d_ws, size_t ws_size,
                              hipStream_t stream) {
    const float* h_init = (const float*)d_in[0];
    const float* W1  = (const float*)d_in[1];
    const float* b1  = (const float*)d_in[2];
    const float* W2  = (const float*)d_in[3];
    const float* Wx  = (const float*)d_in[4];
    const float* bx  = (const float*)d_in[5];
    const float* Wc  = (const float*)d_in[6];
    const float* bc  = (const float*)d_in[7];
    const float* Wv  = (const float*)d_in[8];
    const float* bv  = (const float*)d_in[9];
    const float* Wi  = (const float*)d_in[10];
    const float* Wh  = (const float*)d_in[11];
    const float* bi  = (const float*)d_in[12];
    const float* bh  = (const float*)d_in[13];
    const float* Wp1 = (const float*)d_in[14];
    const float* bp1 = (const float*)d_in[15];
    const float* Wp2 = (const float*)d_in[16];
    const float* gum = (const float*)d_in[17];
    const int* val_idx = (const int*)d_in[18];
    // d_in[19] = cst_idx (known structure: e/8), d_in[20] = steps (device scalar)
    float* out = (float*)d_out;

    const int S = (out_size - 1) / 2;    // log_probs[S], unsat[S], best

    const size_t VH = (size_t)NVAL * HD;
    float* ws     = (float*)d_ws;
    float* h      = ws;
    float* tA     = ws + VH;
    float* tB     = ws + 2 * VH;
    float* rcst   = ws + 3 * VH;
    float* agg    = rcst + (size_t)NCST * HD;
    float* assign = agg + (size_t)NVAR * HD;
    float* logits = assign + NVAL;
    float* lp_acc = logits + NVAL;            // 8 floats
    int*   sat    = (int*)(lp_acc + 8);       // 8 ints
    float* best   = (float*)(sat + 8);        // 1 float

    const size_t needed = ((3 * VH) + (size_t)NCST * HD + (size_t)NVAR * HD +
                           2 * (size_t)NVAL + 32) * sizeof(float);
    if (ws_size < needed) {  // diagnostic: expose ws_size through d_out
        k_report<<<1, 1, 0, stream>>>(out, (float)ws_size);
        return;
    }

    (void)hipMemsetAsync(lp_acc, 0, 17 * sizeof(float), stream);

    const dim3 B256(256);
    const dim3 gV(NVAL / 64);        // 2500
    const dim3 gE(NEDGE / 64);       // 2500
    const dim3 gVar((NVAR + 255) / 256);

    k_init_h<<<dim3(NVAL * HD / 256), B256, 0, stream>>>(h, h_init);
    k_sample<<<gVar, B256, 0, stream>>>(nullptr, gum, assign, lp_acc);
    k_unsat<<<gVar, B256, 0, stream>>>(assign, val_idx, sat);
    k_finalize<<<1, 1, 0, stream>>>(lp_acc, sat, best, out, 0, S, 0);

    for (int s = 0; s < S; ++s) {
        const int t = s + 1;
        // 1. H1 = relu([h[val_idx] | assign_bit] @ W1 + b1) -> tA
        gemm_k<AM_GATHER, AM_NONE, true, true, EPI_STORE><<<gE, B256, 0, stream>>>(
            h, nullptr, val_idx, assign, W1, HD, 0, b1, tA, HD, nullptr, nullptr);
        // 2. r_cst = groupsum8(H1 @ W2)
        gemm_k<AM_DIRECT, AM_NONE, false, false, EPI_RCST><<<gE, B256, 0, stream>>>(
            tA, nullptr, nullptr, nullptr, W2, HD, 0, nullptr, nullptr, HD, rcst, nullptr);
        // 3. x_val = relu(h @ Wx + bx) -> tA
        gemm_k<AM_DIRECT, AM_NONE, false, true, EPI_STORE><<<gV, B256, 0, stream>>>(
            h, nullptr, nullptr, nullptr, Wx, HD, 0, bx, tA, HD, nullptr, nullptr);
        // 4. y_val = scatter_add(relu([r_cst[e/8] | x_val[val_idx]] @ Wc + bc))
        (void)hipMemsetAsync(tB, 0, VH * sizeof(float), stream);
        gemm_k<AM_DIV8, AM_GATHER, false, true, EPI_SCATTER><<<gE, B256, 0, stream>>>(
            rcst, tA, val_idx, nullptr, Wc, HD, 0, bc, tB, HD, nullptr, nullptr);
        // 5. agg = mean over domain
        k_agg<<<dim3(NVAR * HD / 256), B256, 0, stream>>>(tB, agg);
        // 6. z = relu([y_val | agg[v/8]] @ Wv + bv) -> tA
        gemm_k<AM_DIRECT, AM_DIV8, false, true, EPI_STORE><<<gV, B256, 0, stream>>>(
            tB, agg, nullptr, nullptr, Wv, HD, 0, bv, tA, HD, nullptr, nullptr);
        // 7. h = GRU(z, h) (fused, in place, v2)
        k_gru2<<<dim3(NVAL / 64), dim3(1024), 0, stream>>>(tA, h, Wi, Wh, bi, bh);
        // 8. logits = relu(h @ Wp1 + bp1) @ Wp2
        gemm_k<AM_DIRECT, AM_NONE, false, true, EPI_POLICY><<<gV, B256, 0, stream>>>(
            h, nullptr, nullptr, nullptr, Wp1, HD, 0, bp1, nullptr, HD, logits, Wp2);
        // 9. sample / unsat / outputs
        k_sample<<<gVar, B256, 0, stream>>>(logits, gum + (size_t)t * NVAL, assign, lp_acc + t);
        k_unsat<<<gVar, B256, 0, stream>>>(assign, val_idx, sat + t);
        k_finalize<<<1, 1, 0, stream>>>(lp_acc + t, sat + t, best, out, s, S, 1);
    }
}

// Round 3
// 3106.852 us; speedup vs baseline: 7.9298x; 3.2276x over previous
//
#include <hip/hip_runtime.h>
#include <math.h>

#define NVAR  20000
#define NVAL  160000
#define NCST  20000
#define NEDGE 160000
#define HD    128

typedef __attribute__((ext_vector_type(8))) short  short8;   // 8 bf16 (4 VGPRs)
typedef __attribute__((ext_vector_type(4))) float  f32x4;    // MFMA accumulator
typedef __attribute__((ext_vector_type(4))) float  floatx4;

static __device__ __forceinline__ float sigmoidf_(float x) {
    return 1.0f / (1.0f + expf(-x));
}

// f32 -> bf16 bits, round-to-nearest-even
static __device__ __forceinline__ short bf16c(float f) {
    unsigned u = __float_as_uint(f);
    u += 0x7fffu + ((u >> 16) & 1u);
    return (short)(u >> 16);
}

// load 8 f32 from row+k0, convert to bf16 fragment
static __device__ __forceinline__ short8 loadA_f32(const float* __restrict__ row, int k0) {
    floatx4 a = *(const floatx4*)(row + k0);
    floatx4 b = *(const floatx4*)(row + k0 + 4);
    short8 r;
    r[0] = bf16c(a[0]); r[1] = bf16c(a[1]); r[2] = bf16c(a[2]); r[3] = bf16c(a[3]);
    r[4] = bf16c(b[0]); r[5] = bf16c(b[1]); r[6] = bf16c(b[2]); r[7] = bf16c(b[3]);
    return r;
}

// ---------------------------------------------------------------------------
// one-time weight convert+transpose: W[K][N] f32 -> WT[N][K] bf16 (8 matrices)
// ---------------------------------------------------------------------------
struct WD  { const float* W; short* WT; int K; int N; int total; };
struct WDs { WD d[8]; };

__global__ __launch_bounds__(256) void k_wconv8(WDs ds) {
    WD d = ds.d[blockIdx.y];
    int i = blockIdx.x * 256 + threadIdx.x;
    if (i >= d.total) return;
    int n = i / d.K, k = i - n * d.K;
    d.WT[i] = bf16c(d.W[(size_t)k * d.N + n]);
}

// ---------------------------------------------------------------------------
// elementwise / small kernels (unchanged from working f32 version)
// ---------------------------------------------------------------------------

__global__ __launch_bounds__(256) void k_init_h(float* __restrict__ h,
                                                const float* __restrict__ hinit) {
    size_t i = (size_t)blockIdx.x * 256 + threadIdx.x;
    h[i] = hinit[i & (HD - 1)];
}

__global__ __launch_bounds__(256) void k_agg(const float* __restrict__ y,
                                             float* __restrict__ agg) {
    size_t i = (size_t)blockIdx.x * 256 + threadIdx.x;
    int var = (int)(i >> 7);
    int c   = (int)(i & (HD - 1));
    const float* base = y + ((size_t)var * 8) * HD + c;
    float s = 0.f;
#pragma unroll
    for (int d = 0; d < 8; ++d) s += base[(size_t)d * HD];
    agg[i] = s * 0.125f;
}

__global__ __launch_bounds__(256) void k_sample(const float* __restrict__ logits,
                                                const float* __restrict__ g,
                                                float* __restrict__ assign,
                                                float* __restrict__ lp_accum) {
    int v = blockIdx.x * 256 + threadIdx.x;
    float lp = 0.f;
    if (v < NVAR) {
        float lg[8];
        int choice = 0;
        float bestv = -1e30f;
#pragma unroll
        for (int d = 0; d < 8; ++d) {
            lg[d] = logits ? logits[v * 8 + d] : 0.f;
            float t = lg[d] + g[v * 8 + d];
            if (t > bestv) { bestv = t; choice = d; }
        }
        float m = lg[0];
#pragma unroll
        for (int d = 1; d < 8; ++d) m = fmaxf(m, lg[d]);
        float se = 0.f;
#pragma unroll
        for (int d = 0; d < 8; ++d) se += expf(lg[d] - m);
        lp = lg[choice] - m - logf(se);
#pragma unroll
        for (int d = 0; d < 8; ++d) assign[v * 8 + d] = (d == choice) ? 1.f : 0.f;
    }
    __shared__ float sred[256];
    sred[threadIdx.x] = lp;
    __syncthreads();
    for (int o = 128; o > 0; o >>= 1) {
        if (threadIdx.x < o) sred[threadIdx.x] += sred[threadIdx.x + o];
        __syncthreads();
    }
    if (threadIdx.x == 0) atomicAdd(lp_accum, sred[0]);
}

__global__ __launch_bounds__(256) void k_unsat(const float* __restrict__ assign,
                                               const int* __restrict__ val_idx,
                                               int* __restrict__ sat_accum) {
    int c = blockIdx.x * 256 + threadIdx.x;
    int sat = 0;
    if (c < NCST) {
#pragma unroll
        for (int j = 0; j < 8; ++j)
            if (assign[val_idx[c * 8 + j]] > 0.5f) sat = 1;
    }
    __shared__ int sred[256];
    sred[threadIdx.x] = sat;
    __syncthreads();
    for (int o = 128; o > 0; o >>= 1) {
        if (threadIdx.x < o) sred[threadIdx.x] += sred[threadIdx.x + o];
        __syncthreads();
    }
    if (threadIdx.x == 0) atomicAdd(sat_accum, sred[0]);
}

__global__ void k_finalize(const float* __restrict__ lp, const int* __restrict__ sat,
                           float* __restrict__ best, float* __restrict__ out,
                           int s, int S, int mode) {
    float nu = (float)NCST - (float)(*sat);
    if (mode == 0) {
        *best = nu;
    } else {
        out[s] = *lp;
        out[S + s] = nu;
        float b = *best;
        if (nu < b) b = nu;
        *best = b;
        if (s == S - 1) out[2 * S] = b;
    }
}

__global__ void k_report(float* out, float v) {
    for (int i = 0; i < 9; ++i) out[i] = v;
}

// ---------------------------------------------------------------------------
// MFMA GEMM: LDS-free.  Block = 256 thr = 4 waves; wave w owns rows
// rb = bid*64 + w*16, all 128 cols (8 16x16 tiles).  B = WT[n][K] bf16 global
// (L1/L2-resident).  A-frag: lane holds A[rb + (lane&15)][kc*32+(lane>>4)*8 ..+7].
// B-frag: lane holds WT[t*16+(lane&15)][same k] (16B contiguous).
// D layout (m89-verified): col = lane&15, row = (lane>>4)*4 + reg.
// K-slot pairing between A and B fragments is (lane_hi, reg)-symmetric, so the
// shared k-map makes the product exact regardless of HW k-order.
// ---------------------------------------------------------------------------
static constexpr int AM_NONE = 0, AM_DIRECT = 1, AM_GATHER = 2, AM_DIV8 = 3;
static constexpr int EPI_STORE = 0, EPI_RCST = 1, EPI_SCATTER = 2, EPI_POLICY = 3;

template <int A0M, bool A0BF, int A1M, bool A1BF, bool BIT, bool RELU, int EPI, bool OUTBF>
__global__ __launch_bounds__(256)
void gemmM(const void* __restrict__ A0, const void* __restrict__ A1,
           const int* __restrict__ aidx, const float* __restrict__ abit,
           const float* __restrict__ w1r128,
           const short* __restrict__ WT, const float* __restrict__ bias0,
           void* __restrict__ Cout, float* __restrict__ out2,
           const float* __restrict__ wp2) {
    constexpr int K = (A1M == AM_NONE) ? 128 : 256;
    const int tid  = threadIdx.x;
    const int w    = tid >> 6;
    const int lane = tid & 63;
    const int li   = lane & 15;
    const int hi   = lane >> 4;
    const int rb   = blockIdx.x * 64 + w * 16;
    const int ar   = rb + li;                      // A-frag source row

    int ia0 = ar;
    if constexpr (A0M == AM_GATHER)     ia0 = aidx[ar];
    else if constexpr (A0M == AM_DIV8)  ia0 = ar >> 3;
    int ia1 = ar;
    if constexpr (A1M == AM_GATHER)     ia1 = aidx[ar];
    else if constexpr (A1M == AM_DIV8)  ia1 = ar >> 3;

    f32x4 acc[8];
#pragma unroll
    for (int t = 0; t < 8; ++t) acc[t] = (f32x4){0.f, 0.f, 0.f, 0.f};

#pragma unroll
    for (int kc = 0; kc < K / 32; ++kc) {
        short8 af;
        if (kc < 4) {
            const int k0 = kc * 32 + hi * 8;
            if constexpr (A0BF) af = *(const short8*)((const short*)A0 + (size_t)ia0 * HD + k0);
            else                af = loadA_f32((const float*)A0 + (size_t)ia0 * HD, k0);
        } else {
            const int k0 = (kc - 4) * 32 + hi * 8;
            if constexpr (A1BF) af = *(const short8*)((const short*)A1 + (size_t)ia1 * HD + k0);
            else                af = loadA_f32((const float*)A1 + (size_t)ia1 * HD, k0);
        }
#pragma unroll
        for (int t = 0; t < 8; ++t) {
            short8 bf = *(const short8*)(WT + (size_t)(t * 16 + li) * K + kc * 32 + hi * 8);
            acc[t] = __builtin_amdgcn_mfma_f32_16x16x32_bf16(af, bf, acc[t], 0, 0, 0);
        }
    }

    if constexpr (BIT) {   // 129th input row of W1: + assign_bit[row] * W1[128][col]
        float wv[8];
#pragma unroll
        for (int t = 0; t < 8; ++t) wv[t] = w1r128[t * 16 + li];
#pragma unroll
        for (int r = 0; r < 4; ++r) {
            int gr = rb + hi * 4 + r;
            float bitv = abit[aidx[gr]];
#pragma unroll
            for (int t = 0; t < 8; ++t) acc[t][r] += bitv * wv[t];
        }
    }

    if (bias0 != nullptr) {
#pragma unroll
        for (int t = 0; t < 8; ++t) {
            float bv = bias0[t * 16 + li];
#pragma unroll
            for (int r = 0; r < 4; ++r) acc[t][r] += bv;
        }
    }
    if constexpr (RELU) {
#pragma unroll
        for (int t = 0; t < 8; ++t)
#pragma unroll
            for (int r = 0; r < 4; ++r) acc[t][r] = fmaxf(acc[t][r], 0.f);
    }

    if constexpr (EPI == EPI_STORE) {
#pragma unroll
        for (int r = 0; r < 4; ++r) {
            int gr = rb + hi * 4 + r;
            if constexpr (OUTBF) {
                short* o = (short*)Cout + (size_t)gr * HD + li;
#pragma unroll
                for (int t = 0; t < 8; ++t) o[t * 16] = bf16c(acc[t][r]);
            } else {
                float* o = (float*)Cout + (size_t)gr * HD + li;
#pragma unroll
                for (int t = 0; t < 8; ++t) o[t * 16] = acc[t][r];
            }
        }
    } else if constexpr (EPI == EPI_RCST) {
        // wave's 16 rows = 2 constraints (8 rows each); hi0+hi1 -> c0, hi2+hi3 -> c1
#pragma unroll
        for (int t = 0; t < 8; ++t) {
            float s = acc[t][0] + acc[t][1] + acc[t][2] + acc[t][3];
            s += __shfl_xor(s, 16);
            if (hi == 0)      out2[(size_t)(rb >> 3) * HD + t * 16 + li] = s;
            else if (hi == 2) out2[(size_t)((rb >> 3) + 1) * HD + t * 16 + li] = s;
        }
    } else if constexpr (EPI == EPI_SCATTER) {
#pragma unroll
        for (int r = 0; r < 4; ++r) {
            int gr = rb + hi * 4 + r;
            int ix = aidx[gr];
            float* dst = (float*)Cout + (size_t)ix * HD + li;
#pragma unroll
            for (int t = 0; t < 8; ++t) atomicAdd(dst + t * 16, acc[t][r]);
        }
    } else {  // EPI_POLICY: logits[row] = relu-acc dot Wp2
        float wv[8];
#pragma unroll
        for (int t = 0; t < 8; ++t) wv[t] = wp2[t * 16 + li];
#pragma unroll
        for (int r = 0; r < 4; ++r) {
            float p = 0.f;
#pragma unroll
            for (int t = 0; t < 8; ++t) p = fmaf(acc[t][r], wv[t], p);
            p += __shfl_xor(p, 1);
            p += __shfl_xor(p, 2);
            p += __shfl_xor(p, 4);
            p += __shfl_xor(p, 8);
            if (li == 0) out2[rb + hi * 4 + r] = p;
        }
    }
}

// ---------------------------------------------------------------------------
// fused MFMA GRU: h = GRU(z, h) in place.  4 waves x 16 rows; 32 f32x4 accs
// (r,z shared across Wi/Wh passes; n-input and n-hidden kept separate).
// Wave-private row band -> no barriers, in-place safe.
// ---------------------------------------------------------------------------
__global__ __launch_bounds__(256)
void k_gruM(const short* __restrict__ Z, float* __restrict__ Hb,
            const short* __restrict__ WiT, const short* __restrict__ WhT,
            const float* __restrict__ bi, const float* __restrict__ bh) {
    const int tid  = threadIdx.x;
    const int w    = tid >> 6;
    const int lane = tid & 63;
    const int li   = lane & 15;
    const int hi   = lane >> 4;
    const int rb   = blockIdx.x * 64 + w * 16;

    const short* zrow = Z  + (size_t)(rb + li) * HD;
    const float* hrow = Hb + (size_t)(rb + li) * HD;

    f32x4 aR[8], aZ[8], aN[8], aH[8];
#pragma unroll
    for (int t = 0; t < 8; ++t) {
        aR[t] = (f32x4){0.f, 0.f, 0.f, 0.f};
        aZ[t] = (f32x4){0.f, 0.f, 0.f, 0.f};
        aN[t] = (f32x4){0.f, 0.f, 0.f, 0.f};
        aH[t] = (f32x4){0.f, 0.f, 0.f, 0.f};
    }

#pragma unroll
    for (int kc = 0; kc < 4; ++kc) {           // pass 1: Z @ Wi
        const int k0 = kc * 32 + hi * 8;
        short8 af = *(const short8*)(zrow + k0);
#pragma unroll
        for (int t = 0; t < 8; ++t) {
            short8 b0 = *(const short8*)(WiT + (size_t)(t * 16 + li) * HD + k0);
            aR[t] = __builtin_amdgcn_mfma_f32_16x16x32_bf16(af, b0, aR[t], 0, 0, 0);
            short8 b1 = *(const short8*)(WiT + (size_t)(128 + t * 16 + li) * HD + k0);
            aZ[t] = __builtin_amdgcn_mfma_f32_16x16x32_bf16(af, b1, aZ[t], 0, 0, 0);
            short8 b2 = *(const short8*)(WiT + (size_t)(256 + t * 16 + li) * HD + k0);
            aN[t] = __builtin_amdgcn_mfma_f32_16x16x32_bf16(af, b2, aN[t], 0, 0, 0);
        }
    }
#pragma unroll
    for (int kc = 0; kc < 4; ++kc) {           // pass 2: H @ Wh
        const int k0 = kc * 32 + hi * 8;
        short8 af = loadA_f32(hrow, k0);
#pragma unroll
        for (int t = 0; t < 8; ++t) {
            short8 b0 = *(const short8*)(WhT + (size_t)(t * 16 + li) * HD + k0);
            aR[t] = __builtin_amdgcn_mfma_f32_16x16x32_bf16(af, b0, aR[t], 0, 0, 0);
            short8 b1 = *(const short8*)(WhT + (size_t)(128 + t * 16 + li) * HD + k0);
            aZ[t] = __builtin_amdgcn_mfma_f32_16x16x32_bf16(af, b1, aZ[t], 0, 0, 0);
            short8 b2 = *(const short8*)(WhT + (size_t)(256 + t * 16 + li) * HD + k0);
            aH[t] = __builtin_amdgcn_mfma_f32_16x16x32_bf16(af, b2, aH[t], 0, 0, 0);
        }
    }

#pragma unroll
    for (int r = 0; r < 4; ++r) {
        int gr = rb + hi * 4 + r;
        float* hout = Hb + (size_t)gr * HD + li;
#pragma unroll
        for (int t = 0; t < 8; ++t) {
            int c = t * 16 + li;
            float rr = sigmoidf_(aR[t][r] + bi[c] + bh[c]);
            float zz = sigmoidf_(aZ[t][r] + bi[128 + c] + bh[128 + c]);
            float nn = tanhf(aN[t][r] + bi[256 + c] + rr * (aH[t][r] + bh[256 + c]));
            float hv = hout[t * 16];
            hout[t * 16] = (1.f - zz) * nn + zz * hv;
        }
    }
}

// ---------------------------------------------------------------------------
extern "C" void kernel_launch(void* const* d_in, const int* in_sizes, int n_in,
                              void* d_out, int out_size, void* d_ws, size_t ws_size,
                              hipStream_t stream) {
    const float* h_init = (const float*)d_in[0];
    const float* W1  = (const float*)d_in[1];
    const float* b1  = (const float*)d_in[2];
    const float* W2  = (const float*)d_in[3];
    const float* Wx  = (const float*)d_in[4];
    const float* bx  = (const float*)d_in[5];
    const float* Wc  = (const float*)d_in[6];
    const float* bc  = (const float*)d_in[7];
    const float* Wv  = (const float*)d_in[8];
    const float* bv  = (const float*)d_in[9];
    const float* Wi  = (const float*)d_in[10];
    const float* Wh  = (const float*)d_in[11];
    const float* bi  = (const float*)d_in[12];
    const float* bh  = (const float*)d_in[13];
    const float* Wp1 = (const float*)d_in[14];
    const float* bp1 = (const float*)d_in[15];
    const float* Wp2 = (const float*)d_in[16];
    const float* gum = (const float*)d_in[17];
    const int* val_idx = (const int*)d_in[18];
    float* out = (float*)d_out;

    const int S = (out_size - 1) / 2;

    const size_t VH = (size_t)NVAL * HD;
    float* ws     = (float*)d_ws;
    float* h      = ws;                               // VH f32
    short* tA     = (short*)(ws + VH);                // VH bf16  (VH/2 float slots)
    float* tB     = ws + VH + VH / 2;                 // VH f32
    float* rcst   = tB + VH;                          // NCST*HD
    float* agg    = rcst + (size_t)NCST * HD;         // NVAR*HD
    float* assign = agg + (size_t)NVAR * HD;          // NVAL
    float* logits = assign + NVAL;                    // NVAL
    float* lp_acc = logits + NVAL;                    // 8
    int*   sat    = (int*)(lp_acc + 8);               // 8
    float* best   = (float*)(sat + 8);                // 1 (+pad to 32)
    short* wbase  = (short*)(lp_acc + 32);
    short* W1T  = wbase;                 // 128x128
    short* W2T  = W1T  + 16384;
    short* WxT  = W2T  + 16384;
    short* Wp1T = WxT  + 16384;
    short* WcT  = Wp1T + 16384;          // 128 x 256
    short* WvT  = WcT  + 32768;
    short* WiT  = WvT  + 32768;          // 384 x 128
    short* WhT  = WiT  + 49152;

    const size_t needed = ((2 * VH + VH / 2) + (size_t)NCST * HD + (size_t)NVAR * HD +
                           2 * (size_t)NVAL + 32 + (229376 / 2)) * sizeof(float);
    if (ws_size < needed) {
        k_report<<<1, 1, 0, stream>>>(out, (float)ws_size);
        return;
    }

    // one-time weight transpose+bf16 conversion (constant across steps)
    WDs ds;
    ds.d[0] = { W1,  W1T,  128, 128, 16384 };   // rows 0..127 of W1 (row 128 via rank-1)
    ds.d[1] = { W2,  W2T,  128, 128, 16384 };
    ds.d[2] = { Wx,  WxT,  128, 128, 16384 };
    ds.d[3] = { Wp1, Wp1T, 128, 128, 16384 };
    ds.d[4] = { Wc,  WcT,  256, 128, 32768 };
    ds.d[5] = { Wv,  WvT,  256, 128, 32768 };
    ds.d[6] = { Wi,  WiT,  128, 384, 49152 };
    ds.d[7] = { Wh,  WhT,  128, 384, 49152 };
    k_wconv8<<<dim3(192, 8), dim3(256), 0, stream>>>(ds);

    (void)hipMemsetAsync(lp_acc, 0, 17 * sizeof(float), stream);

    const dim3 B256(256);
    const dim3 gT(NVAL / 64);        // 2500 blocks for both NVAL and NEDGE
    const dim3 gVar((NVAR + 255) / 256);
    const float* w1r128 = W1 + (size_t)128 * HD;

    k_init_h<<<dim3(NVAL * HD / 256), B256, 0, stream>>>(h, h_init);
    k_sample<<<gVar, B256, 0, stream>>>(nullptr, gum, assign, lp_acc);
    k_unsat<<<gVar, B256, 0, stream>>>(assign, val_idx, sat);
    k_finalize<<<1, 1, 0, stream>>>(lp_acc, sat, best, out, 0, S, 0);

    for (int s = 0; s < S; ++s) {
        const int t = s + 1;
        // 1. tA(bf16) = relu([h[val_idx] | bit] @ W1 + b1)
        gemmM<AM_GATHER, false, AM_NONE, false, true, true, EPI_STORE, true>
            <<<gT, B256, 0, stream>>>(h, nullptr, val_idx, assign, w1r128,
                                      W1T, b1, tA, nullptr, nullptr);
        // 2. rcst = groupsum8(tA @ W2)
        gemmM<AM_DIRECT, true, AM_NONE, false, false, false, EPI_RCST, false>
            <<<gT, B256, 0, stream>>>(tA, nullptr, nullptr, nullptr, nullptr,
                                      W2T, nullptr, nullptr, rcst, nullptr);
        // 3. tA(bf16) = x_val = relu(h @ Wx + bx)
        gemmM<AM_DIRECT, false, AM_NONE, false, false, true, EPI_STORE, true>
            <<<gT, B256, 0, stream>>>(h, nullptr, nullptr, nullptr, nullptr,
                                      WxT, bx, tA, nullptr, nullptr);
        // 4. tB = scatter_add(relu([rcst[e/8] | x_val[val_idx]] @ Wc + bc))
        (void)hipMemsetAsync(tB, 0, VH * sizeof(float), stream);
        gemmM<AM_DIV8, false, AM_GATHER, true, false, true, EPI_SCATTER, false>
            <<<gT, B256, 0, stream>>>(rcst, tA, val_idx, nullptr, nullptr,
                                      WcT, bc, tB, nullptr, nullptr);
        // 5. agg = domain mean
        k_agg<<<dim3(NVAR * HD / 256), B256, 0, stream>>>(tB, agg);
        // 6. tA(bf16) = z = relu([tB | agg[v/8]] @ Wv + bv)
        gemmM<AM_DIRECT, false, AM_DIV8, false, false, true, EPI_STORE, true>
            <<<gT, B256, 0, stream>>>(tB, agg, nullptr, nullptr, nullptr,
                                      WvT, bv, tA, nullptr, nullptr);
        // 7. h = GRU(z, h)
        k_gruM<<<gT, B256, 0, stream>>>(tA, h, WiT, WhT, bi, bh);
        // 8. logits = relu(h @ Wp1 + bp1) @ Wp2
        gemmM<AM_DIRECT, false, AM_NONE, false, false, true, EPI_POLICY, false>
            <<<gT, B256, 0, stream>>>(h, nullptr, nullptr, nullptr, nullptr,
                                      Wp1T, bp1, nullptr, logits, Wp2);
        // 9. sample / unsat / outputs
        k_sample<<<gVar, B256, 0, stream>>>(logits, gum + (size_t)t * NVAL, assign, lp_acc + t);
        k_unsat<<<gVar, B256, 0, stream>>>(assign, val_idx, sat + t);
        k_finalize<<<1, 1, 0, stream>>>(lp_acc + t, sat + t, best, out, s, S, 1);
    }
}

// Round 4
// 1780.569 us; speedup vs baseline: 13.8365x; 1.7449x over previous
//
#include <hip/hip_runtime.h>
#include <math.h>

#define NVAR  20000
#define NVAL  160000
#define NCST  20000
#define NEDGE 160000
#define HD    128

typedef __attribute__((ext_vector_type(8))) short  short8;   // 8 bf16 (4 VGPRs)
typedef __attribute__((ext_vector_type(4))) float  f32x4;    // MFMA accumulator
typedef __attribute__((ext_vector_type(4))) float  floatx4;

static __device__ __forceinline__ float sigmoidf_(float x) {
    return 1.0f / (1.0f + expf(-x));
}

// f32 -> bf16 bits, round-to-nearest-even
static __device__ __forceinline__ short bf16c(float f) {
    unsigned u = __float_as_uint(f);
    u += 0x7fffu + ((u >> 16) & 1u);
    return (short)(u >> 16);
}
static __device__ __forceinline__ float bf2f(unsigned short b) {
    return __uint_as_float(((unsigned)b) << 16);
}

// load 8 f32 from row+k0, convert to bf16 fragment
static __device__ __forceinline__ short8 loadA_f32(const float* __restrict__ row, int k0) {
    floatx4 a = *(const floatx4*)(row + k0);
    floatx4 b = *(const floatx4*)(row + k0 + 4);
    short8 r;
    r[0] = bf16c(a[0]); r[1] = bf16c(a[1]); r[2] = bf16c(a[2]); r[3] = bf16c(a[3]);
    r[4] = bf16c(b[0]); r[5] = bf16c(b[1]); r[6] = bf16c(b[2]); r[7] = bf16c(b[3]);
    return r;
}

// ---------------------------------------------------------------------------
// one-time weight convert+transpose: W[K][N] f32 -> WT[N][K] bf16 (8 matrices)
// ---------------------------------------------------------------------------
struct WD  { const float* W; short* WT; int K; int N; int total; };
struct WDs { WD d[8]; };

__global__ __launch_bounds__(256) void k_wconv8(WDs ds) {
    WD d = ds.d[blockIdx.y];
    int i = blockIdx.x * 256 + threadIdx.x;
    if (i >= d.total) return;
    int n = i / d.K, k = i - n * d.K;
    d.WT[i] = bf16c(d.W[(size_t)k * d.N + n]);
}

// ---------------------------------------------------------------------------
// elementwise / small kernels
// ---------------------------------------------------------------------------

__global__ __launch_bounds__(256) void k_init_hb(short* __restrict__ h,
                                                 const float* __restrict__ hinit) {
    size_t i = (size_t)blockIdx.x * 256 + threadIdx.x;
    h[i] = bf16c(hinit[i & (HD - 1)]);
}

__global__ __launch_bounds__(256) void k_agg(const float* __restrict__ y,
                                             short* __restrict__ agg) {
    size_t i = (size_t)blockIdx.x * 256 + threadIdx.x;   // over NVAR*HD
    int var = (int)(i >> 7);
    int c   = (int)(i & (HD - 1));
    const float* base = y + ((size_t)var * 8) * HD + c;
    float s = 0.f;
#pragma unroll
    for (int d = 0; d < 8; ++d) s += base[(size_t)d * HD];
    agg[i] = bf16c(s * 0.125f);
}

__global__ __launch_bounds__(256) void k_sample(const float* __restrict__ logits,
                                                const float* __restrict__ g,
                                                float* __restrict__ assign,
                                                float* __restrict__ lp_accum) {
    int v = blockIdx.x * 256 + threadIdx.x;
    float lp = 0.f;
    if (v < NVAR) {
        float lg[8];
        int choice = 0;
        float bestv = -1e30f;
#pragma unroll
        for (int d = 0; d < 8; ++d) {
            lg[d] = logits ? logits[v * 8 + d] : 0.f;
            float t = lg[d] + g[v * 8 + d];
            if (t > bestv) { bestv = t; choice = d; }
        }
        float m = lg[0];
#pragma unroll
        for (int d = 1; d < 8; ++d) m = fmaxf(m, lg[d]);
        float se = 0.f;
#pragma unroll
        for (int d = 0; d < 8; ++d) se += expf(lg[d] - m);
        lp = lg[choice] - m - logf(se);
#pragma unroll
        for (int d = 0; d < 8; ++d) assign[v * 8 + d] = (d == choice) ? 1.f : 0.f;
    }
    __shared__ float sred[256];
    sred[threadIdx.x] = lp;
    __syncthreads();
    for (int o = 128; o > 0; o >>= 1) {
        if (threadIdx.x < o) sred[threadIdx.x] += sred[threadIdx.x + o];
        __syncthreads();
    }
    if (threadIdx.x == 0) atomicAdd(lp_accum, sred[0]);
}

__global__ __launch_bounds__(256) void k_unsat(const float* __restrict__ assign,
                                               const int* __restrict__ val_idx,
                                               int* __restrict__ sat_accum) {
    int c = blockIdx.x * 256 + threadIdx.x;
    int sat = 0;
    if (c < NCST) {
#pragma unroll
        for (int j = 0; j < 8; ++j)
            if (assign[val_idx[c * 8 + j]] > 0.5f) sat = 1;
    }
    __shared__ int sred[256];
    sred[threadIdx.x] = sat;
    __syncthreads();
    for (int o = 128; o > 0; o >>= 1) {
        if (threadIdx.x < o) sred[threadIdx.x] += sred[threadIdx.x + o];
        __syncthreads();
    }
    if (threadIdx.x == 0) atomicAdd(sat_accum, sred[0]);
}

__global__ void k_finalize(const float* __restrict__ lp, const int* __restrict__ sat,
                           float* __restrict__ best, float* __restrict__ out,
                           int s, int S, int mode) {
    float nu = (float)NCST - (float)(*sat);
    if (mode == 0) {
        *best = nu;
    } else {
        out[s] = *lp;
        out[S + s] = nu;
        float b = *best;
        if (nu < b) b = nu;
        *best = b;
        if (s == S - 1) out[2 * S] = b;
    }
}

__global__ void k_report(float* out, float v) {
    for (int i = 0; i < 9; ++i) out[i] = v;
}

// ---------------------------------------------------------------------------
// Persistent-B MFMA GEMM, K=128, full 128 output cols per wave.
// B (WT, 128x128 bf16 = 32KB) hoisted into 32 short8 VGPRs per wave ONCE;
// grid-stride over 16-row tiles: inner loop = 4 A-loads + 32 MFMAs.
// A is always bf16 [rows][128].  D layout: col=lane&15, row=(lane>>4)*4+reg.
// ---------------------------------------------------------------------------
static constexpr int AM_DIRECT = 1, AM_GATHER = 2, AM_DIV8 = 3;
static constexpr int EPI_STORE = 0, EPI_RCST = 1, EPI_SCATTER = 2, EPI_POLICY = 3;

template <int A0M, bool BIT, bool RELU, int EPI>
__global__ __launch_bounds__(256)
void k_gemmA(const short* __restrict__ A, const int* __restrict__ aidx,
             const float* __restrict__ abit, const float* __restrict__ w1r128,
             const short* __restrict__ WT, const float* __restrict__ bias0,
             short* __restrict__ outBF, short* __restrict__ rcstOut,
             float* __restrict__ logitsOut, const float* __restrict__ wp2) {
    const int tid  = threadIdx.x;
    const int w    = tid >> 6;
    const int lane = tid & 63;
    const int li   = lane & 15;
    const int hi   = lane >> 4;

    short8 Bf[8][4];
#pragma unroll
    for (int t = 0; t < 8; ++t)
#pragma unroll
        for (int kc = 0; kc < 4; ++kc)
            Bf[t][kc] = *(const short8*)(WT + (size_t)(t * 16 + li) * 128 + kc * 32 + hi * 8);

    float bv[8];
#pragma unroll
    for (int t = 0; t < 8; ++t) bv[t] = bias0 ? bias0[t * 16 + li] : 0.f;
    float wv[8];
    if constexpr (BIT) {
#pragma unroll
        for (int t = 0; t < 8; ++t) wv[t] = w1r128[t * 16 + li];
    }
    float wpv[8];
    if constexpr (EPI == EPI_POLICY) {
#pragma unroll
        for (int t = 0; t < 8; ++t) wpv[t] = wp2[t * 16 + li];
    }

    const int stride = gridDim.x * 4;
    for (int rt = blockIdx.x * 4 + w; rt < NVAL / 16; rt += stride) {
        const int ar = rt * 16 + li;
        int ia = ar;
        if constexpr (A0M == AM_GATHER) ia = aidx[ar];
        const short8* arow = (const short8*)(A + (size_t)ia * HD);

        short8 af[4];
#pragma unroll
        for (int kc = 0; kc < 4; ++kc) af[kc] = arow[kc * 4 + hi];

        f32x4 acc[8];
#pragma unroll
        for (int t = 0; t < 8; ++t) acc[t] = (f32x4){0.f, 0.f, 0.f, 0.f};
#pragma unroll
        for (int kc = 0; kc < 4; ++kc)
#pragma unroll
            for (int t = 0; t < 8; ++t)
                acc[t] = __builtin_amdgcn_mfma_f32_16x16x32_bf16(af[kc], Bf[t][kc], acc[t], 0, 0, 0);

        if constexpr (BIT) {
#pragma unroll
            for (int r = 0; r < 4; ++r) {
                int gr = rt * 16 + hi * 4 + r;
                float bitv = abit[aidx[gr]];
#pragma unroll
                for (int t = 0; t < 8; ++t) acc[t][r] += bitv * wv[t];
            }
        }
#pragma unroll
        for (int t = 0; t < 8; ++t)
#pragma unroll
            for (int r = 0; r < 4; ++r) {
                acc[t][r] += bv[t];
                if constexpr (RELU) acc[t][r] = fmaxf(acc[t][r], 0.f);
            }

        if constexpr (EPI == EPI_STORE) {
#pragma unroll
            for (int r = 0; r < 4; ++r) {
                int gr = rt * 16 + hi * 4 + r;
                short* o = outBF + (size_t)gr * HD + li;
#pragma unroll
                for (int t = 0; t < 8; ++t) o[t * 16] = bf16c(acc[t][r]);
            }
        } else if constexpr (EPI == EPI_RCST) {
            // 16 rows = 2 constraints; hi{0,1}->c0, hi{2,3}->c1
#pragma unroll
            for (int t = 0; t < 8; ++t) {
                float s = acc[t][0] + acc[t][1] + acc[t][2] + acc[t][3];
                s += __shfl_xor(s, 16);
                if (hi == 0)      rcstOut[(size_t)(rt * 2) * HD + t * 16 + li]     = bf16c(s);
                else if (hi == 2) rcstOut[(size_t)(rt * 2 + 1) * HD + t * 16 + li] = bf16c(s);
            }
        } else {  // EPI_POLICY
#pragma unroll
            for (int r = 0; r < 4; ++r) {
                float p = 0.f;
#pragma unroll
                for (int t = 0; t < 8; ++t) p = fmaf(acc[t][r], wpv[t], p);
                p += __shfl_xor(p, 1);
                p += __shfl_xor(p, 2);
                p += __shfl_xor(p, 4);
                p += __shfl_xor(p, 8);
                if (li == 0) logitsOut[rt * 16 + hi * 4 + r] = p;
            }
        }
    }
}

// ---------------------------------------------------------------------------
// Persistent-B MFMA GEMM, K=256, 64 output cols per wave (2 col-halves via
// grid).  B half = 32 short8.  A = [A0 (k<128) | A1 (k>=128)].
// ---------------------------------------------------------------------------
template <bool A0F32, int A0M, int A1M, bool RELU, int EPI>
__global__ __launch_bounds__(256)
void k_gemmB(const void* __restrict__ A0, const short* __restrict__ A1,
             const int* __restrict__ aidx,
             const short* __restrict__ WT, const float* __restrict__ bias0,
             float* __restrict__ outF32, short* __restrict__ outBF) {
    const int tid  = threadIdx.x;
    const int w    = tid >> 6;
    const int lane = tid & 63;
    const int li   = lane & 15;
    const int hi   = lane >> 4;
    const int ch   = blockIdx.x & 1;          // col half
    const int rba  = blockIdx.x >> 1;

    short8 Bf[4][8];
#pragma unroll
    for (int t = 0; t < 4; ++t)
#pragma unroll
        for (int kc = 0; kc < 8; ++kc)
            Bf[t][kc] = *(const short8*)(WT + (size_t)(ch * 64 + t * 16 + li) * 256 + kc * 32 + hi * 8);

    float bv[4];
#pragma unroll
    for (int t = 0; t < 4; ++t) bv[t] = bias0[ch * 64 + t * 16 + li];

    const int stride = (gridDim.x >> 1) * 4;
    for (int rt = rba * 4 + w; rt < NVAL / 16; rt += stride) {
        const int ar = rt * 16 + li;
        int ia0 = ar, ia1 = ar;
        if constexpr (A0M == AM_DIV8)   ia0 = ar >> 3;
        if constexpr (A1M == AM_GATHER) ia1 = aidx[ar];
        else if constexpr (A1M == AM_DIV8) ia1 = ar >> 3;

        short8 af[8];
        if constexpr (A0F32) {
            const float* r0 = (const float*)A0 + (size_t)ia0 * HD;
#pragma unroll
            for (int kc = 0; kc < 4; ++kc) af[kc] = loadA_f32(r0, kc * 32 + hi * 8);
        } else {
            const short8* r0 = (const short8*)((const short*)A0 + (size_t)ia0 * HD);
#pragma unroll
            for (int kc = 0; kc < 4; ++kc) af[kc] = r0[kc * 4 + hi];
        }
        {
            const short8* r1 = (const short8*)(A1 + (size_t)ia1 * HD);
#pragma unroll
            for (int kc = 0; kc < 4; ++kc) af[4 + kc] = r1[kc * 4 + hi];
        }

        f32x4 acc[4];
#pragma unroll
        for (int t = 0; t < 4; ++t) acc[t] = (f32x4){0.f, 0.f, 0.f, 0.f};
#pragma unroll
        for (int kc = 0; kc < 8; ++kc)
#pragma unroll
            for (int t = 0; t < 4; ++t)
                acc[t] = __builtin_amdgcn_mfma_f32_16x16x32_bf16(af[kc], Bf[t][kc], acc[t], 0, 0, 0);

#pragma unroll
        for (int t = 0; t < 4; ++t)
#pragma unroll
            for (int r = 0; r < 4; ++r) {
                acc[t][r] += bv[t];
                if constexpr (RELU) acc[t][r] = fmaxf(acc[t][r], 0.f);
            }

        if constexpr (EPI == EPI_SCATTER) {
#pragma unroll
            for (int r = 0; r < 4; ++r) {
                int gr = rt * 16 + hi * 4 + r;
                int ix = aidx[gr];
                float* dst = outF32 + (size_t)ix * HD + ch * 64 + li;
#pragma unroll
                for (int t = 0; t < 4; ++t) atomicAdd(dst + t * 16, acc[t][r]);
            }
        } else {  // EPI_STORE -> bf16
#pragma unroll
            for (int r = 0; r < 4; ++r) {
                int gr = rt * 16 + hi * 4 + r;
                short* o = outBF + (size_t)gr * HD + ch * 64 + li;
#pragma unroll
                for (int t = 0; t < 4; ++t) o[t * 16] = bf16c(acc[t][r]);
            }
        }
    }
}

// ---------------------------------------------------------------------------
// Persistent-B fused GRU: hNew = GRU(Z, hOld), bf16 in/out, ping-pong (no
// in-place race under the 4-way col-split).  Wave owns 32 output cols
// (col group g = bid&3): B = 2 tiles x 3 slabs x 4 kc x {Wi,Wh} = 48 short8.
// Adjacent blocks (same row chunk, different g) share Z/H rows via L2.
// ---------------------------------------------------------------------------
__global__ __launch_bounds__(256)
void k_gruP(const short* __restrict__ Z, const short* __restrict__ Hold,
            short* __restrict__ Hnew,
            const short* __restrict__ WiT, const short* __restrict__ WhT,
            const float* __restrict__ bi, const float* __restrict__ bh) {
    const int tid  = threadIdx.x;
    const int w    = tid >> 6;
    const int lane = tid & 63;
    const int li   = lane & 15;
    const int hi   = lane >> 4;
    const int g    = blockIdx.x & 3;
    const int rba  = blockIdx.x >> 2;

    short8 Wif[3][2][4], Whf[3][2][4];
#pragma unroll
    for (int s = 0; s < 3; ++s)
#pragma unroll
        for (int u = 0; u < 2; ++u)
#pragma unroll
            for (int kc = 0; kc < 4; ++kc) {
                size_t off = (size_t)(s * 128 + g * 32 + u * 16 + li) * 128 + kc * 32 + hi * 8;
                Wif[s][u][kc] = *(const short8*)(WiT + off);
                Whf[s][u][kc] = *(const short8*)(WhT + off);
            }

    float bR[2], bZ[2], bIN[2], bHN[2];
#pragma unroll
    for (int u = 0; u < 2; ++u) {
        int c = g * 32 + u * 16 + li;
        bR[u]  = bi[c] + bh[c];
        bZ[u]  = bi[128 + c] + bh[128 + c];
        bIN[u] = bi[256 + c];
        bHN[u] = bh[256 + c];
    }

    const int stride = (gridDim.x >> 2) * 4;
    for (int rt = rba * 4 + w; rt < NVAL / 16; rt += stride) {
        const short8* zrow = (const short8*)(Z    + (size_t)(rt * 16 + li) * HD);
        const short8* hrow = (const short8*)(Hold + (size_t)(rt * 16 + li) * HD);
        short8 zf[4], hf[4];
#pragma unroll
        for (int kc = 0; kc < 4; ++kc) { zf[kc] = zrow[kc * 4 + hi]; hf[kc] = hrow[kc * 4 + hi]; }

        f32x4 aR[2], aZ[2], aN[2], aH[2];
#pragma unroll
        for (int u = 0; u < 2; ++u) {
            aR[u] = (f32x4){0.f, 0.f, 0.f, 0.f};
            aZ[u] = (f32x4){0.f, 0.f, 0.f, 0.f};
            aN[u] = (f32x4){0.f, 0.f, 0.f, 0.f};
            aH[u] = (f32x4){0.f, 0.f, 0.f, 0.f};
        }
#pragma unroll
        for (int kc = 0; kc < 4; ++kc)
#pragma unroll
            for (int u = 0; u < 2; ++u) {
                aR[u] = __builtin_amdgcn_mfma_f32_16x16x32_bf16(zf[kc], Wif[0][u][kc], aR[u], 0, 0, 0);
                aZ[u] = __builtin_amdgcn_mfma_f32_16x16x32_bf16(zf[kc], Wif[1][u][kc], aZ[u], 0, 0, 0);
                aN[u] = __builtin_amdgcn_mfma_f32_16x16x32_bf16(zf[kc], Wif[2][u][kc], aN[u], 0, 0, 0);
            }
#pragma unroll
        for (int kc = 0; kc < 4; ++kc)
#pragma unroll
            for (int u = 0; u < 2; ++u) {
                aR[u] = __builtin_amdgcn_mfma_f32_16x16x32_bf16(hf[kc], Whf[0][u][kc], aR[u], 0, 0, 0);
                aZ[u] = __builtin_amdgcn_mfma_f32_16x16x32_bf16(hf[kc], Whf[1][u][kc], aZ[u], 0, 0, 0);
                aH[u] = __builtin_amdgcn_mfma_f32_16x16x32_bf16(hf[kc], Whf[2][u][kc], aH[u], 0, 0, 0);
            }

#pragma unroll
        for (int r = 0; r < 4; ++r) {
            int gr = rt * 16 + hi * 4 + r;
#pragma unroll
            for (int u = 0; u < 2; ++u) {
                int c = g * 32 + u * 16 + li;
                float hv = bf2f(((const unsigned short*)Hold)[(size_t)gr * HD + c]);
                float rr = sigmoidf_(aR[u][r] + bR[u]);
                float zz = sigmoidf_(aZ[u][r] + bZ[u]);
                float nn = tanhf(aN[u][r] + bIN[u] + rr * (aH[u][r] + bHN[u]));
                Hnew[(size_t)gr * HD + c] = bf16c((1.f - zz) * nn + zz * hv);
            }
        }
    }
}

// ---------------------------------------------------------------------------
extern "C" void kernel_launch(void* const* d_in, const int* in_sizes, int n_in,
                              void* d_out, int out_size, void* d_ws, size_t ws_size,
                              hipStream_t stream) {
    const float* h_init = (const float*)d_in[0];
    const float* W1  = (const float*)d_in[1];
    const float* b1  = (const float*)d_in[2];
    const float* W2  = (const float*)d_in[3];
    const float* Wx  = (const float*)d_in[4];
    const float* bx  = (const float*)d_in[5];
    const float* Wc  = (const float*)d_in[6];
    const float* bc  = (const float*)d_in[7];
    const float* Wv  = (const float*)d_in[8];
    const float* bv  = (const float*)d_in[9];
    const float* Wi  = (const float*)d_in[10];
    const float* Wh  = (const float*)d_in[11];
    const float* bi  = (const float*)d_in[12];
    const float* bh  = (const float*)d_in[13];
    const float* Wp1 = (const float*)d_in[14];
    const float* bp1 = (const float*)d_in[15];
    const float* Wp2 = (const float*)d_in[16];
    const float* gum = (const float*)d_in[17];
    const int* val_idx = (const int*)d_in[18];
    float* out = (float*)d_out;

    const int S = (out_size - 1) / 2;

    const size_t VH = (size_t)NVAL * HD;
    short* hbA    = (short*)d_ws;                     // VH bf16
    short* hbB    = hbA + VH;                         // VH bf16
    short* tA     = hbB + VH;                         // VH bf16
    float* tB     = (float*)(tA + VH);                // VH f32
    float* assign = tB + VH;                          // NVAL f32
    float* logits = assign + NVAL;                    // NVAL f32
    short* rcst   = (short*)(logits + NVAL);          // NCST*HD bf16
    short* aggb   = rcst + (size_t)NCST * HD;         // NVAR*HD bf16
    short* W1T  = aggb + (size_t)NVAR * HD;           // 128x128
    short* W2T  = W1T  + 16384;
    short* WxT  = W2T  + 16384;
    short* Wp1T = WxT  + 16384;
    short* WcT  = Wp1T + 16384;                       // 128 x 256
    short* WvT  = WcT  + 32768;
    short* WiT  = WvT  + 32768;                       // 384 x 128
    short* WhT  = WiT  + 49152;
    float* lp_acc = (float*)(WhT + 49152);            // 8 f32
    int*   sat    = (int*)(lp_acc + 8);               // 8 int
    float* best   = (float*)(sat + 8);                // 8 f32

    const size_t needed = (size_t)((char*)(best + 8) - (char*)d_ws);
    if (ws_size < needed) {
        k_report<<<1, 1, 0, stream>>>(out, (float)ws_size);
        return;
    }

    WDs ds;
    ds.d[0] = { W1,  W1T,  128, 128, 16384 };   // rows 0..127 (row 128 via rank-1)
    ds.d[1] = { W2,  W2T,  128, 128, 16384 };
    ds.d[2] = { Wx,  WxT,  128, 128, 16384 };
    ds.d[3] = { Wp1, Wp1T, 128, 128, 16384 };
    ds.d[4] = { Wc,  WcT,  256, 128, 32768 };
    ds.d[5] = { Wv,  WvT,  256, 128, 32768 };
    ds.d[6] = { Wi,  WiT,  128, 384, 49152 };
    ds.d[7] = { Wh,  WhT,  128, 384, 49152 };
    k_wconv8<<<dim3(192, 8), dim3(256), 0, stream>>>(ds);

    (void)hipMemsetAsync(lp_acc, 0, 24 * sizeof(float), stream);

    const dim3 B256(256);
    const dim3 gA(640);        // K=128 persistent-B GEMMs
    const dim3 gB(1280);       // K=256, 2 col-halves
    const dim3 gG(1024);       // GRU, 4 col-groups
    const dim3 gVar((NVAR + 255) / 256);
    const float* w1r128 = W1 + (size_t)128 * HD;

    k_init_hb<<<dim3(NVAL * HD / 256), B256, 0, stream>>>(hbA, h_init);
    k_sample<<<gVar, B256, 0, stream>>>(nullptr, gum, assign, lp_acc);
    k_unsat<<<gVar, B256, 0, stream>>>(assign, val_idx, sat);
    k_finalize<<<1, 1, 0, stream>>>(lp_acc, sat, best, out, 0, S, 0);

    for (int s = 0; s < S; ++s) {
        const int t = s + 1;
        const short* hcur = (s & 1) ? hbB : hbA;
        short*       hnxt = (s & 1) ? hbA : hbB;
        // 1. tA = relu([h[val_idx] | bit] @ W1 + b1)
        k_gemmA<AM_GATHER, true, true, EPI_STORE><<<gA, B256, 0, stream>>>(
            hcur, val_idx, assign, w1r128, W1T, b1, tA, nullptr, nullptr, nullptr);
        // 2. rcst = groupsum8(tA @ W2)
        k_gemmA<AM_DIRECT, false, false, EPI_RCST><<<gA, B256, 0, stream>>>(
            tA, nullptr, nullptr, nullptr, W2T, nullptr, nullptr, rcst, nullptr, nullptr);
        // 3. tA = x_val = relu(h @ Wx + bx)
        k_gemmA<AM_DIRECT, false, true, EPI_STORE><<<gA, B256, 0, stream>>>(
            hcur, nullptr, nullptr, nullptr, WxT, bx, tA, nullptr, nullptr, nullptr);
        // 4. tB = scatter_add(relu([rcst[e/8] | x_val[val_idx]] @ Wc + bc))
        (void)hipMemsetAsync(tB, 0, VH * sizeof(float), stream);
        k_gemmB<false, AM_DIV8, AM_GATHER, true, EPI_SCATTER><<<gB, B256, 0, stream>>>(
            rcst, tA, val_idx, WcT, bc, tB, nullptr);
        // 5. agg = domain mean (bf16)
        k_agg<<<dim3(NVAR * HD / 256), B256, 0, stream>>>(tB, aggb);
        // 6. tA = z = relu([tB | agg[v/8]] @ Wv + bv)
        k_gemmB<true, AM_DIRECT, AM_DIV8, true, EPI_STORE><<<gB, B256, 0, stream>>>(
            tB, aggb, nullptr, WvT, bv, nullptr, tA);
        // 7. hnxt = GRU(z, hcur)
        k_gruP<<<gG, B256, 0, stream>>>(tA, hcur, hnxt, WiT, WhT, bi, bh);
        // 8. logits = relu(hnxt @ Wp1 + bp1) @ Wp2
        k_gemmA<AM_DIRECT, false, true, EPI_POLICY><<<gA, B256, 0, stream>>>(
            hnxt, nullptr, nullptr, nullptr, Wp1T, bp1, nullptr, nullptr, logits, Wp2);
        // 9. sample / unsat / outputs
        k_sample<<<gVar, B256, 0, stream>>>(logits, gum + (size_t)t * NVAL, assign, lp_acc + t);
        k_unsat<<<gVar, B256, 0, stream>>>(assign, val_idx, sat + t);
        k_finalize<<<1, 1, 0, stream>>>(lp_acc + t, sat + t, best, out, s, S, 1);
    }
}

// Round 5
// 1608.973 us; speedup vs baseline: 15.3121x; 1.1066x over previous
//
#include <hip/hip_runtime.h>
#include <math.h>

#define NVAR  20000
#define NVAL  160000
#define NCST  20000
#define HD    128
#define NT16  10000    // NVAL/16 row-tiles

typedef __attribute__((ext_vector_type(8))) short  short8;   // 8 bf16 (4 VGPRs)
typedef __attribute__((ext_vector_type(4))) float  f32x4;    // MFMA accumulator
typedef __attribute__((ext_vector_type(4))) float  floatx4;

// fast gates: v_exp_f32 + v_rcp_f32 paths (tolerance is 2% — plenty)
static __device__ __forceinline__ float sigf(float x) {
    return __fdividef(1.0f, 1.0f + __expf(-x));
}
static __device__ __forceinline__ float tanhf_(float x) {
    return 1.0f - __fdividef(2.0f, 1.0f + __expf(2.0f * x));
}

// f32 -> bf16 bits, round-to-nearest-even
static __device__ __forceinline__ short bf16c(float f) {
    unsigned u = __float_as_uint(f);
    u += 0x7fffu + ((u >> 16) & 1u);
    return (short)(u >> 16);
}
static __device__ __forceinline__ float bf2f(unsigned short b) {
    return __uint_as_float(((unsigned)b) << 16);
}
static __device__ __forceinline__ short8 pack8(floatx4 a, floatx4 b) {
    short8 r;
    r[0] = bf16c(a[0]); r[1] = bf16c(a[1]); r[2] = bf16c(a[2]); r[3] = bf16c(a[3]);
    r[4] = bf16c(b[0]); r[5] = bf16c(b[1]); r[6] = bf16c(b[2]); r[7] = bf16c(b[3]);
    return r;
}

// ---------------------------------------------------------------------------
// one-time weight convert+transpose: W[K][N] f32 -> WT[N][K] bf16 (8 matrices)
// ---------------------------------------------------------------------------
struct WD  { const float* W; short* WT; int K; int N; int total; };
struct WDs { WD d[8]; };

__global__ __launch_bounds__(256) void k_wconv8(WDs ds) {
    WD d = ds.d[blockIdx.y];
    int i = blockIdx.x * 256 + threadIdx.x;
    if (i >= d.total) return;
    int n = i / d.K, k = i - n * d.K;
    d.WT[i] = bf16c(d.W[(size_t)k * d.N + n]);
}

// ---------------------------------------------------------------------------
// small kernels
// ---------------------------------------------------------------------------
__global__ __launch_bounds__(256) void k_init_hb(short* __restrict__ h,
                                                 const float* __restrict__ hinit) {
    size_t i = (size_t)blockIdx.x * 256 + threadIdx.x;
    h[i] = bf16c(hinit[i & (HD - 1)]);
}

__global__ __launch_bounds__(256) void k_sample(const float* __restrict__ logits,
                                                const float* __restrict__ g,
                                                float* __restrict__ assign,
                                                float* __restrict__ lp_accum) {
    int v = blockIdx.x * 256 + threadIdx.x;
    float lp = 0.f;
    if (v < NVAR) {
        float lg[8];
        int choice = 0;
        float bestv = -1e30f;
#pragma unroll
        for (int d = 0; d < 8; ++d) {
            lg[d] = logits ? logits[v * 8 + d] : 0.f;
            float t = lg[d] + g[v * 8 + d];
            if (t > bestv) { bestv = t; choice = d; }
        }
        float m = lg[0];
#pragma unroll
        for (int d = 1; d < 8; ++d) m = fmaxf(m, lg[d]);
        float se = 0.f;
#pragma unroll
        for (int d = 0; d < 8; ++d) se += __expf(lg[d] - m);
        lp = lg[choice] - m - __logf(se);
#pragma unroll
        for (int d = 0; d < 8; ++d) assign[v * 8 + d] = (d == choice) ? 1.f : 0.f;
    }
    __shared__ float sred[256];
    sred[threadIdx.x] = lp;
    __syncthreads();
    for (int o = 128; o > 0; o >>= 1) {
        if (threadIdx.x < o) sred[threadIdx.x] += sred[threadIdx.x + o];
        __syncthreads();
    }
    if (threadIdx.x == 0) atomicAdd(lp_accum, sred[0]);
}

__global__ __launch_bounds__(256) void k_unsat(const float* __restrict__ assign,
                                               const int* __restrict__ val_idx,
                                               int* __restrict__ sat_accum) {
    int c = blockIdx.x * 256 + threadIdx.x;
    int sat = 0;
    if (c < NCST) {
#pragma unroll
        for (int j = 0; j < 8; ++j)
            if (assign[val_idx[c * 8 + j]] > 0.5f) sat = 1;
    }
    __shared__ int sred[256];
    sred[threadIdx.x] = sat;
    __syncthreads();
    for (int o = 128; o > 0; o >>= 1) {
        if (threadIdx.x < o) sred[threadIdx.x] += sred[threadIdx.x + o];
        __syncthreads();
    }
    if (threadIdx.x == 0) atomicAdd(sat_accum, sred[0]);
}

__global__ void k_finalize(const float* __restrict__ lp, const int* __restrict__ sat,
                           float* __restrict__ best, float* __restrict__ out,
                           int s, int S, int mode) {
    float nu = (float)NCST - (float)(*sat);
    if (mode == 0) {
        *best = nu;
    } else {
        out[s] = *lp;
        out[S + s] = nu;
        float b = *best;
        if (nu < b) b = nu;
        *best = b;
        if (s == S - 1) out[2 * S] = b;
    }
}

__global__ void k_report(float* out, float v) {
    for (int i = 0; i < 9; ++i) out[i] = v;
}

// ---------------------------------------------------------------------------
// Persistent-B MFMA GEMM, K=128, full 128 output cols per wave.
// B hoisted into 32 short8; grid-stride over 16-row tiles (nrows runtime).
// EPI_RCST now = "sum groups of 8 rows" (used PRE-W2 thanks to linearity).
// ---------------------------------------------------------------------------
static constexpr int AM_DIRECT = 1, AM_GATHER = 2;
static constexpr int EPI_STORE = 0, EPI_RCST = 1, EPI_POLICY = 3;

template <int A0M, bool BIT, bool RELU, int EPI>
__global__ __launch_bounds__(256)
void k_gemmA(const short* __restrict__ A, const int* __restrict__ aidx,
             const float* __restrict__ abit, const float* __restrict__ w1r128,
             const short* __restrict__ WT, const float* __restrict__ bias0,
             short* __restrict__ outBF, short* __restrict__ rcstOut,
             float* __restrict__ logitsOut, const float* __restrict__ wp2,
             int nrows) {
    const int tid  = threadIdx.x;
    const int w    = tid >> 6;
    const int lane = tid & 63;
    const int li   = lane & 15;
    const int hi   = lane >> 4;

    short8 Bf[8][4];
#pragma unroll
    for (int t = 0; t < 8; ++t)
#pragma unroll
        for (int kc = 0; kc < 4; ++kc)
            Bf[t][kc] = *(const short8*)(WT + (size_t)(t * 16 + li) * 128 + kc * 32 + hi * 8);

    float bv[8];
#pragma unroll
    for (int t = 0; t < 8; ++t) bv[t] = bias0 ? bias0[t * 16 + li] : 0.f;
    float wv[8];
    if constexpr (BIT) {
#pragma unroll
        for (int t = 0; t < 8; ++t) wv[t] = w1r128[t * 16 + li];
    }
    float wpv[8];
    if constexpr (EPI == EPI_POLICY) {
#pragma unroll
        for (int t = 0; t < 8; ++t) wpv[t] = wp2[t * 16 + li];
    }

    const int nt = nrows >> 4;
    const int stride = gridDim.x * 4;
    for (int rt = blockIdx.x * 4 + w; rt < nt; rt += stride) {
        const int ar = rt * 16 + li;
        int ia = ar;
        if constexpr (A0M == AM_GATHER) ia = aidx[ar];
        const short8* arow = (const short8*)(A + (size_t)ia * HD);

        short8 af[4];
#pragma unroll
        for (int kc = 0; kc < 4; ++kc) af[kc] = arow[kc * 4 + hi];

        f32x4 acc[8];
#pragma unroll
        for (int t = 0; t < 8; ++t) acc[t] = (f32x4){0.f, 0.f, 0.f, 0.f};
#pragma unroll
        for (int kc = 0; kc < 4; ++kc)
#pragma unroll
            for (int t = 0; t < 8; ++t)
                acc[t] = __builtin_amdgcn_mfma_f32_16x16x32_bf16(af[kc], Bf[t][kc], acc[t], 0, 0, 0);

        if constexpr (BIT) {
#pragma unroll
            for (int r = 0; r < 4; ++r) {
                int gr = rt * 16 + hi * 4 + r;
                float bitv = abit[aidx[gr]];
#pragma unroll
                for (int t = 0; t < 8; ++t) acc[t][r] += bitv * wv[t];
            }
        }
#pragma unroll
        for (int t = 0; t < 8; ++t)
#pragma unroll
            for (int r = 0; r < 4; ++r) {
                acc[t][r] += bv[t];
                if constexpr (RELU) acc[t][r] = fmaxf(acc[t][r], 0.f);
            }

        if constexpr (EPI == EPI_STORE) {
#pragma unroll
            for (int r = 0; r < 4; ++r) {
                int gr = rt * 16 + hi * 4 + r;
                short* o = outBF + (size_t)gr * HD + li;
#pragma unroll
                for (int t = 0; t < 8; ++t) o[t * 16] = bf16c(acc[t][r]);
            }
        } else if constexpr (EPI == EPI_RCST) {
            // 16 rows = 2 groups of 8; hi{0,1}->g0, hi{2,3}->g1
#pragma unroll
            for (int t = 0; t < 8; ++t) {
                float s = acc[t][0] + acc[t][1] + acc[t][2] + acc[t][3];
                s += __shfl_xor(s, 16);
                if (hi == 0)      rcstOut[(size_t)(rt * 2) * HD + t * 16 + li]     = bf16c(s);
                else if (hi == 2) rcstOut[(size_t)(rt * 2 + 1) * HD + t * 16 + li] = bf16c(s);
            }
        } else {  // EPI_POLICY
#pragma unroll
            for (int r = 0; r < 4; ++r) {
                float p = 0.f;
#pragma unroll
                for (int t = 0; t < 8; ++t) p = fmaf(acc[t][r], wpv[t], p);
                p += __shfl_xor(p, 1);
                p += __shfl_xor(p, 2);
                p += __shfl_xor(p, 4);
                p += __shfl_xor(p, 8);
                if (li == 0) logitsOut[rt * 16 + hi * 4 + r] = p;
            }
        }
    }
}

// ---------------------------------------------------------------------------
// scatter GEMM (step 4): y_e = relu([rcst[e/8] | x_val[val_idx]] @ Wc + bc),
// atomicAdd into tB[val_idx].  K=256, col-half ch = bid>>10 (same-row pair on
// same XCD), rba = bid & 1023.
// ---------------------------------------------------------------------------
__global__ __launch_bounds__(256)
void k_scat(const short* __restrict__ rcst, const short* __restrict__ tA,
            const int* __restrict__ val_idx,
            const short* __restrict__ WcT, const float* __restrict__ bc,
            float* __restrict__ tB) {
    const int tid  = threadIdx.x;
    const int w    = tid >> 6;
    const int lane = tid & 63;
    const int li   = lane & 15;
    const int hi   = lane >> 4;
    const int ch   = blockIdx.x >> 10;
    const int rba  = blockIdx.x & 1023;

    short8 Bf[4][8];
#pragma unroll
    for (int t = 0; t < 4; ++t)
#pragma unroll
        for (int kc = 0; kc < 8; ++kc)
            Bf[t][kc] = *(const short8*)(WcT + (size_t)(ch * 64 + t * 16 + li) * 256 + kc * 32 + hi * 8);

    float bv[4];
#pragma unroll
    for (int t = 0; t < 4; ++t) bv[t] = bc[ch * 64 + t * 16 + li];

    for (int rt = rba * 4 + w; rt < NT16; rt += 4096) {
        const int ar = rt * 16 + li;
        const short8* r0 = (const short8*)(rcst + (size_t)(ar >> 3) * HD);
        const short8* r1 = (const short8*)(tA + (size_t)val_idx[ar] * HD);
        short8 af[8];
#pragma unroll
        for (int kc = 0; kc < 4; ++kc) { af[kc] = r0[kc * 4 + hi]; af[4 + kc] = r1[kc * 4 + hi]; }

        f32x4 acc[4];
#pragma unroll
        for (int t = 0; t < 4; ++t) acc[t] = (f32x4){0.f, 0.f, 0.f, 0.f};
#pragma unroll
        for (int kc = 0; kc < 8; ++kc)
#pragma unroll
            for (int t = 0; t < 4; ++t)
                acc[t] = __builtin_amdgcn_mfma_f32_16x16x32_bf16(af[kc], Bf[t][kc], acc[t], 0, 0, 0);

#pragma unroll
        for (int r = 0; r < 4; ++r) {
            int gr = rt * 16 + hi * 4 + r;
            int ix = val_idx[gr];
            float* dst = tB + (size_t)ix * HD + ch * 64 + li;
#pragma unroll
            for (int t = 0; t < 4; ++t)
                atomicAdd(dst + t * 16, fmaxf(acc[t][r] + bv[t], 0.f));
        }
    }
}

// ---------------------------------------------------------------------------
// fused agg + z GEMM (steps 5+6): z = relu([tB | mean8(tB)] @ Wv + bv).
// The 16 rows a tile loads ARE the 2 variables it needs means for: 3
// shfl_xor rounds over li bits build the agg fragment in-register.
// ---------------------------------------------------------------------------
__global__ __launch_bounds__(256)
void k_gemmZ(const float* __restrict__ tB, const short* __restrict__ WvT,
             const float* __restrict__ bvv, short* __restrict__ outT) {
    const int tid  = threadIdx.x;
    const int w    = tid >> 6;
    const int lane = tid & 63;
    const int li   = lane & 15;
    const int hi   = lane >> 4;
    const int ch   = blockIdx.x >> 10;
    const int rba  = blockIdx.x & 1023;

    short8 Bf[4][8];
#pragma unroll
    for (int t = 0; t < 4; ++t)
#pragma unroll
        for (int kc = 0; kc < 8; ++kc)
            Bf[t][kc] = *(const short8*)(WvT + (size_t)(ch * 64 + t * 16 + li) * 256 + kc * 32 + hi * 8);

    float bv[4];
#pragma unroll
    for (int t = 0; t < 4; ++t) bv[t] = bvv[ch * 64 + t * 16 + li];

    for (int rt = rba * 4 + w; rt < NT16; rt += 4096) {
        const int ar = rt * 16 + li;
        const float* row = tB + (size_t)ar * HD;
        floatx4 a[8], m[8];
#pragma unroll
        for (int q = 0; q < 8; ++q) {
            a[q] = *(const floatx4*)(row + (q >> 1) * 32 + hi * 8 + (q & 1) * 4);
            m[q] = a[q];
        }
        // sum over the 8 rows of this lane's variable (li bits 0..2)
#pragma unroll
        for (int q = 0; q < 8; ++q)
#pragma unroll
            for (int e = 0; e < 4; ++e) {
                m[q][e] += __shfl_xor(m[q][e], 1);
                m[q][e] += __shfl_xor(m[q][e], 2);
                m[q][e] += __shfl_xor(m[q][e], 4);
                m[q][e] *= 0.125f;
            }

        short8 af[8];
#pragma unroll
        for (int kc = 0; kc < 4; ++kc) {
            af[kc]     = pack8(a[2 * kc], a[2 * kc + 1]);
            af[4 + kc] = pack8(m[2 * kc], m[2 * kc + 1]);
        }

        f32x4 acc[4];
#pragma unroll
        for (int t = 0; t < 4; ++t) acc[t] = (f32x4){0.f, 0.f, 0.f, 0.f};
#pragma unroll
        for (int kc = 0; kc < 8; ++kc)
#pragma unroll
            for (int t = 0; t < 4; ++t)
                acc[t] = __builtin_amdgcn_mfma_f32_16x16x32_bf16(af[kc], Bf[t][kc], acc[t], 0, 0, 0);

#pragma unroll
        for (int r = 0; r < 4; ++r) {
            int gr = rt * 16 + hi * 4 + r;
            short* o = outT + (size_t)gr * HD + ch * 64 + li;
#pragma unroll
            for (int t = 0; t < 4; ++t)
                o[t * 16] = bf16c(fmaxf(acc[t][r] + bv[t], 0.f));
        }
    }
}

// ---------------------------------------------------------------------------
// Persistent-B fused GRU: hNew = GRU(Z, hOld), bf16 ping-pong.
// Wave owns 16 output cols (g = bid>>8, 8 groups): B = 3 slabs x {Wi,Wh} x
// 4 kc = 24 short8 = 96 VGPR -> truly register-resident.  g as the SLOW
// blockIdx field keeps the 8 col-groups of a row range on one XCD (bid%8
// = XCD round-robin) so Z/H rows are L2-shared.  Next tile's fragments are
// prefetched over the gate epilogue.  Fast-math gates.
// ---------------------------------------------------------------------------
__global__ __launch_bounds__(256)
void k_gruQ(const short* __restrict__ Z, const short* __restrict__ Hold,
            short* __restrict__ Hnew,
            const short* __restrict__ WiT, const short* __restrict__ WhT,
            const float* __restrict__ bi, const float* __restrict__ bh) {
    const int tid  = threadIdx.x;
    const int w    = tid >> 6;
    const int lane = tid & 63;
    const int li   = lane & 15;
    const int hi   = lane >> 4;
    const int g    = blockIdx.x >> 8;     // 0..7 col group (16 cols)
    const int rba  = blockIdx.x & 255;

    short8 Bi_[3][4], Bh_[3][4];
#pragma unroll
    for (int s = 0; s < 3; ++s)
#pragma unroll
        for (int kc = 0; kc < 4; ++kc) {
            size_t off = (size_t)(s * 128 + g * 16 + li) * 128 + kc * 32 + hi * 8;
            Bi_[s][kc] = *(const short8*)(WiT + off);
            Bh_[s][kc] = *(const short8*)(WhT + off);
        }

    const int c = g * 16 + li;
    const float bR  = bi[c] + bh[c];
    const float bZg = bi[128 + c] + bh[128 + c];
    const float bIN = bi[256 + c];
    const float bHN = bh[256 + c];

    const int stride = 1024;              // 256 row-blocks * 4 waves
    int rt = rba * 4 + w;
    short8 zf[4], hf[4];
    if (rt < NT16) {
        const short8* zr = (const short8*)(Z    + (size_t)(rt * 16 + li) * HD);
        const short8* hr = (const short8*)(Hold + (size_t)(rt * 16 + li) * HD);
#pragma unroll
        for (int kc = 0; kc < 4; ++kc) { zf[kc] = zr[kc * 4 + hi]; hf[kc] = hr[kc * 4 + hi]; }
    }
    while (rt < NT16) {
        const int rtn = rt + stride;

        f32x4 aR = {0.f,0.f,0.f,0.f}, aZ = {0.f,0.f,0.f,0.f};
        f32x4 aN = {0.f,0.f,0.f,0.f}, aH = {0.f,0.f,0.f,0.f};
#pragma unroll
        for (int kc = 0; kc < 4; ++kc) {
            aR = __builtin_amdgcn_mfma_f32_16x16x32_bf16(zf[kc], Bi_[0][kc], aR, 0, 0, 0);
            aZ = __builtin_amdgcn_mfma_f32_16x16x32_bf16(zf[kc], Bi_[1][kc], aZ, 0, 0, 0);
            aN = __builtin_amdgcn_mfma_f32_16x16x32_bf16(zf[kc], Bi_[2][kc], aN, 0, 0, 0);
        }
#pragma unroll
        for (int kc = 0; kc < 4; ++kc) {
            aR = __builtin_amdgcn_mfma_f32_16x16x32_bf16(hf[kc], Bh_[0][kc], aR, 0, 0, 0);
            aZ = __builtin_amdgcn_mfma_f32_16x16x32_bf16(hf[kc], Bh_[1][kc], aZ, 0, 0, 0);
            aH = __builtin_amdgcn_mfma_f32_16x16x32_bf16(hf[kc], Bh_[2][kc], aH, 0, 0, 0);
        }

        // prefetch next tile's fragments over the gate epilogue
        short8 zfn[4], hfn[4];
        const bool vn = rtn < NT16;
        if (vn) {
            const short8* zr = (const short8*)(Z    + (size_t)(rtn * 16 + li) * HD);
            const short8* hr = (const short8*)(Hold + (size_t)(rtn * 16 + li) * HD);
#pragma unroll
            for (int kc = 0; kc < 4; ++kc) { zfn[kc] = zr[kc * 4 + hi]; hfn[kc] = hr[kc * 4 + hi]; }
        }

#pragma unroll
        for (int r = 0; r < 4; ++r) {
            int gr = rt * 16 + hi * 4 + r;
            float hv = bf2f(((const unsigned short*)Hold)[(size_t)gr * HD + c]);
            float rr = sigf(aR[r] + bR);
            float zz = sigf(aZ[r] + bZg);
            float nn = tanhf_(aN[r] + bIN + rr * (aH[r] + bHN));
            Hnew[(size_t)gr * HD + c] = bf16c((1.f - zz) * nn + zz * hv);
        }

        if (vn) {
#pragma unroll
            for (int kc = 0; kc < 4; ++kc) { zf[kc] = zfn[kc]; hf[kc] = hfn[kc]; }
        }
        rt = rtn;
    }
}

// ---------------------------------------------------------------------------
extern "C" void kernel_launch(void* const* d_in, const int* in_sizes, int n_in,
                              void* d_out, int out_size, void* d_ws, size_t ws_size,
                              hipStream_t stream) {
    const float* h_init = (const float*)d_in[0];
    const float* W1  = (const float*)d_in[1];
    const float* b1  = (const float*)d_in[2];
    const float* W2  = (const float*)d_in[3];
    const float* Wx  = (const float*)d_in[4];
    const float* bx  = (const float*)d_in[5];
    const float* Wc  = (const float*)d_in[6];
    const float* bc  = (const float*)d_in[7];
    const float* Wv  = (const float*)d_in[8];
    const float* bv  = (const float*)d_in[9];
    const float* Wi  = (const float*)d_in[10];
    const float* Wh  = (const float*)d_in[11];
    const float* bi  = (const float*)d_in[12];
    const float* bh  = (const float*)d_in[13];
    const float* Wp1 = (const float*)d_in[14];
    const float* bp1 = (const float*)d_in[15];
    const float* Wp2 = (const float*)d_in[16];
    const float* gum = (const float*)d_in[17];
    const int* val_idx = (const int*)d_in[18];
    float* out = (float*)d_out;

    const int S = (out_size - 1) / 2;

    const size_t VH = (size_t)NVAL * HD;
    short* hbA    = (short*)d_ws;                     // VH bf16
    short* hbB    = hbA + VH;                         // VH bf16
    short* tA     = hbB + VH;                         // VH bf16
    float* tB     = (float*)(tA + VH);                // VH f32
    float* assign = tB + VH;                          // NVAL f32
    float* logits = assign + NVAL;                    // NVAL f32
    short* s_cst  = (short*)(logits + NVAL);          // NCST*HD bf16 (pre-W2 sums)
    short* rcst   = s_cst + (size_t)NCST * HD;        // NCST*HD bf16
    short* W1T  = rcst + (size_t)NCST * HD;           // 128x128
    short* W2T  = W1T  + 16384;
    short* WxT  = W2T  + 16384;
    short* Wp1T = WxT  + 16384;
    short* WcT  = Wp1T + 16384;                       // 128 x 256
    short* WvT  = WcT  + 32768;
    short* WiT  = WvT  + 32768;                       // 384 x 128
    short* WhT  = WiT  + 49152;
    float* lp_acc = (float*)(WhT + 49152);            // 8 f32
    int*   sat    = (int*)(lp_acc + 8);               // 8 int
    float* best   = (float*)(sat + 8);                // 8 f32

    const size_t needed = (size_t)((char*)(best + 8) - (char*)d_ws);
    if (ws_size < needed) {
        k_report<<<1, 1, 0, stream>>>(out, (float)ws_size);
        return;
    }

    WDs ds;
    ds.d[0] = { W1,  W1T,  128, 128, 16384 };   // rows 0..127 (row 128 via rank-1)
    ds.d[1] = { W2,  W2T,  128, 128, 16384 };
    ds.d[2] = { Wx,  WxT,  128, 128, 16384 };
    ds.d[3] = { Wp1, Wp1T, 128, 128, 16384 };
    ds.d[4] = { Wc,  WcT,  256, 128, 32768 };
    ds.d[5] = { Wv,  WvT,  256, 128, 32768 };
    ds.d[6] = { Wi,  WiT,  128, 384, 49152 };
    ds.d[7] = { Wh,  WhT,  128, 384, 49152 };
    k_wconv8<<<dim3(192, 8), dim3(256), 0, stream>>>(ds);

    (void)hipMemsetAsync(lp_acc, 0, 24 * sizeof(float), stream);

    const dim3 B256(256);
    const dim3 gA(640);        // K=128 GEMMs over NVAL rows
    const dim3 gW(160);        // W2 GEMM over NCST rows
    const dim3 gB(2048);       // K=256 kernels (2 col halves, XCD-paired)
    const dim3 gG(2048);       // GRU (8 col groups, XCD-grouped)
    const dim3 gVar((NVAR + 255) / 256);
    const float* w1r128 = W1 + (size_t)128 * HD;

    k_init_hb<<<dim3(NVAL * HD / 256), B256, 0, stream>>>(hbA, h_init);
    k_sample<<<gVar, B256, 0, stream>>>(nullptr, gum, assign, lp_acc);
    k_unsat<<<gVar, B256, 0, stream>>>(assign, val_idx, sat);
    k_finalize<<<1, 1, 0, stream>>>(lp_acc, sat, best, out, 0, S, 0);

    for (int s = 0; s < S; ++s) {
        const int t = s + 1;
        const short* hcur = (s & 1) ? hbB : hbA;
        short*       hnxt = (s & 1) ? hbA : hbB;
        // 1+2a. s_cst = sum8(relu([h[val_idx] | bit] @ W1 + b1))   (linearity)
        k_gemmA<AM_GATHER, true, true, EPI_RCST><<<gA, B256, 0, stream>>>(
            hcur, val_idx, assign, w1r128, W1T, b1, nullptr, s_cst, nullptr, nullptr, NVAL);
        // 2b. rcst = s_cst @ W2   (20000 rows only)
        k_gemmA<AM_DIRECT, false, false, EPI_STORE><<<gW, B256, 0, stream>>>(
            s_cst, nullptr, nullptr, nullptr, W2T, nullptr, rcst, nullptr, nullptr, nullptr, NCST);
        // 3. tA = x_val = relu(h @ Wx + bx)
        k_gemmA<AM_DIRECT, false, true, EPI_STORE><<<gA, B256, 0, stream>>>(
            hcur, nullptr, nullptr, nullptr, WxT, bx, tA, nullptr, nullptr, nullptr, NVAL);
        // 4. tB = scatter_add(relu([rcst[e/8] | x_val[val_idx]] @ Wc + bc))
        (void)hipMemsetAsync(tB, 0, VH * sizeof(float), stream);
        k_scat<<<gB, B256, 0, stream>>>(rcst, tA, val_idx, WcT, bc, tB);
        // 5+6. tA = z = relu([tB | mean8(tB)] @ Wv + bv)   (agg fused in-register)
        k_gemmZ<<<gB, B256, 0, stream>>>(tB, WvT, bv, tA);
        // 7. hnxt = GRU(z, hcur)
        k_gruQ<<<gG, B256, 0, stream>>>(tA, hcur, hnxt, WiT, WhT, bi, bh);
        // 8. logits = relu(hnxt @ Wp1 + bp1) @ Wp2
        k_gemmA<AM_DIRECT, false, true, EPI_POLICY><<<gA, B256, 0, stream>>>(
            hnxt, nullptr, nullptr, nullptr, Wp1T, bp1, nullptr, nullptr, logits, Wp2, NVAL);
        // 9. sample / unsat / outputs
        k_sample<<<gVar, B256, 0, stream>>>(logits, gum + (size_t)t * NVAL, assign, lp_acc + t);
        k_unsat<<<gVar, B256, 0, stream>>>(assign, val_idx, sat + t);
        k_finalize<<<1, 1, 0, stream>>>(lp_acc + t, sat + t, best, out, s, S, 1);
    }
}